// Round 3
// baseline (1359.463 us; speedup 1.0000x reference)
//
#include <hip/hip_runtime.h>
#include <stdint.h>

// ---------------------------------------------------------------------------
// ColorExtractor: per-image k-means (B=64, N=224*224, C=3, K=16, 10 iters).
// Threefry2x32 bit-exact (verified R1, absmax 0.0).
// R3: single mega-kernel, 512 blocks co-resident (launch_bounds(256,2) ->
// 2 blocks/CU guaranteed), software grid barrier (agent-scope atomics),
// parallel hist scan + binary search (kills kinit_b's 152us serial scan),
// triple-buffered f64 sums -> 1 barrier per k-means iteration, redundant
// per-block update (kills kupdate dispatches). 25 dispatches -> 2.
// ---------------------------------------------------------------------------

#define NB    64
#define NPIX  50176
#define NK    16
#define NCH   3
#define NITER 10
#define HBINS 2048
#define CANDCAP 1024     // expect ~320 cands/batch (T2VAL), 1024 = >30 sigma
#define COLLCAP 128      // expect ~24.5/bin, 128 = >20 sigma
#define NBLK  512        // 8 chunks x 64 batches; 2 blocks/CU on 256 CUs
#define CHUNK (NPIX / 8) // 6272 px per block-chunk
#define NQUAD (CHUNK / 4)

typedef unsigned long long u64;

struct KeyPair { uint32_t a, b; };

__device__ __forceinline__ uint32_t rotl32(uint32_t v, uint32_t r) {
  return (v << r) | (v >> (32u - r));
}
__device__ __forceinline__ void tf_round(uint32_t& x0, uint32_t& x1, uint32_t r) {
  x0 += x1; x1 = rotl32(x1, r); x1 ^= x0;
}

// Threefry-2x32, 20 rounds, exactly as jax/_src/prng.py lowering.
__device__ __forceinline__ KeyPair threefry(uint32_t k0, uint32_t k1,
                                            uint32_t x0, uint32_t x1) {
  const uint32_t ks2 = k0 ^ k1 ^ 0x1BD11BDAu;
  x0 += k0; x1 += k1;
  tf_round(x0, x1, 13u); tf_round(x0, x1, 15u); tf_round(x0, x1, 26u); tf_round(x0, x1, 6u);
  x0 += k1;  x1 += ks2 + 1u;
  tf_round(x0, x1, 17u); tf_round(x0, x1, 29u); tf_round(x0, x1, 16u); tf_round(x0, x1, 24u);
  x0 += ks2; x1 += k0 + 2u;
  tf_round(x0, x1, 13u); tf_round(x0, x1, 15u); tf_round(x0, x1, 26u); tf_round(x0, x1, 6u);
  x0 += k0;  x1 += k1 + 3u;
  tf_round(x0, x1, 17u); tf_round(x0, x1, 29u); tf_round(x0, x1, 16u); tf_round(x0, x1, 24u);
  x0 += k1;  x1 += ks2 + 4u;
  tf_round(x0, x1, 13u); tf_round(x0, x1, 15u); tf_round(x0, x1, 26u); tf_round(x0, x1, 6u);
  x0 += ks2; x1 += k0 + 5u;
  KeyPair r; r.a = x0; r.b = x1; return r;
}

__device__ __forceinline__ uint32_t sortkey(KeyPair S, uint32_t i) {
  KeyPair r = threefry(S.a, S.b, 0u, i);   // counter = 64-bit iota (hi=0,lo=i)
  return r.a ^ r.b;                        // 32-bit path XOR-folds the block
}

__device__ __forceinline__ void derive_keys(int b, KeyPair& S1, KeyPair& S2) {
  KeyPair root; root.a = 0u; root.b = 42u;
  KeyPair kb = threefry(root.a, root.b, 0u, (uint32_t)b);   // foldlike split
  KeyPair K1 = threefry(kb.a, kb.b, 0u, 0u);
  S1 = threefry(kb.a, kb.b, 0u, 1u);                        // round-1 subkey
  S2 = threefry(K1.a, K1.b, 0u, 1u);                        // round-2 subkey
}

#define T2VAL 27394240u  // ~2^32*320/NPIX

// ---- agent-scope (cross-XCD coherent) accessors ---------------------------
__device__ __forceinline__ void ast_u64(u64* p, u64 v) {
  __hip_atomic_store(p, v, __ATOMIC_RELAXED, __HIP_MEMORY_SCOPE_AGENT);
}
__device__ __forceinline__ u64 ald_u64(const u64* p) {
  return __hip_atomic_load(p, __ATOMIC_RELAXED, __HIP_MEMORY_SCOPE_AGENT);
}
__device__ __forceinline__ void ast_u32(uint32_t* p, uint32_t v) {
  __hip_atomic_store(p, v, __ATOMIC_RELAXED, __HIP_MEMORY_SCOPE_AGENT);
}
__device__ __forceinline__ uint32_t ald_u32(const uint32_t* p) {
  return __hip_atomic_load(p, __ATOMIC_RELAXED, __HIP_MEMORY_SCOPE_AGENT);
}
__device__ __forceinline__ void ast_f32(float* p, float v) {
  __hip_atomic_store(p, v, __ATOMIC_RELAXED, __HIP_MEMORY_SCOPE_AGENT);
}
__device__ __forceinline__ float ald_f32(const float* p) {
  return __hip_atomic_load(p, __ATOMIC_RELAXED, __HIP_MEMORY_SCOPE_AGENT);
}
__device__ __forceinline__ void ast_f64(double* p, double v) {
  __hip_atomic_store(p, v, __ATOMIC_RELAXED, __HIP_MEMORY_SCOPE_AGENT);
}
__device__ __forceinline__ double ald_f64(const double* p) {
  return __hip_atomic_load(p, __ATOMIC_RELAXED, __HIP_MEMORY_SCOPE_AGENT);
}

// Grid barrier: counter + generation, agent scope. Release-sequence on cnt
// RMWs -> gen release -> spinner acquire gives full cross-block visibility.
__device__ __forceinline__ void gbar(uint32_t* cnt, uint32_t* gen) {
  __syncthreads();
  if (threadIdx.x == 0) {
    uint32_t g = __hip_atomic_load(gen, __ATOMIC_RELAXED, __HIP_MEMORY_SCOPE_AGENT);
    uint32_t old = __hip_atomic_fetch_add(cnt, 1u, __ATOMIC_ACQ_REL,
                                          __HIP_MEMORY_SCOPE_AGENT);
    if (old == (uint32_t)NBLK - 1u) {
      __hip_atomic_store(cnt, 0u, __ATOMIC_RELAXED, __HIP_MEMORY_SCOPE_AGENT);
      __hip_atomic_fetch_add(gen, 1u, __ATOMIC_RELEASE, __HIP_MEMORY_SCOPE_AGENT);
    } else {
      while (__hip_atomic_load(gen, __ATOMIC_ACQUIRE,
                               __HIP_MEMORY_SCOPE_AGENT) == g)
        __builtin_amdgcn_s_sleep(1);
    }
  }
  __syncthreads();
}

union SMem {
  struct { uint32_t lh[HBINS]; } p1;
  struct { u64 sc[CANDCAP]; uint32_t sh[HBINS]; uint32_t S[HBINS];
           uint32_t ts[256]; uint32_t Rt[NK]; } p2;
  struct { uint32_t bs[NK]; } p3;
  struct { u64 lc[NK * COLLCAP]; int jsel[NK]; } p4;
  struct { float cs[NK * NCH]; double raw[NK * 4]; double acc[4][NK * 4];
           int knan; } p5;
};

__global__ __launch_bounds__(256, 2) void mega(
    const float* __restrict__ x, float* __restrict__ out,
    float* __restrict__ cent, double* __restrict__ sums,
    uint32_t* __restrict__ ncand, uint32_t* __restrict__ ncoll,
    uint32_t* __restrict__ bar, uint32_t* __restrict__ hist,
    uint32_t* __restrict__ binsel, uint32_t* __restrict__ rem,
    u64* __restrict__ cand, u64* __restrict__ coll) {
  __shared__ SMem sm;
  const int blk = (int)blockIdx.x;
  const int tid = (int)threadIdx.x;
  const int b = blk >> 3;        // batch
  const int c = blk & 7;         // chunk within batch
  uint32_t* cnt_ = bar;
  uint32_t* gen_ = bar + 1;

  KeyPair S1, S2;
  derive_keys(b, S1, S2);

  // ---- P1: key2 candidate filter + key1 prefix histogram ----
  for (int i = tid; i < HBINS; i += 256) sm.p1.lh[i] = 0u;
  __syncthreads();
  {
    const int start = c * CHUNK;
    for (int i = start + tid; i < start + CHUNK; i += 256) {
      uint32_t k2 = sortkey(S2, (uint32_t)i);
      if (k2 < T2VAL) {
        uint32_t p = atomicAdd(&ncand[b], 1u);
        if (p < CANDCAP) ast_u64(&cand[b * CANDCAP + p], ((u64)k2 << 32) | (uint32_t)i);
      }
      uint32_t k1 = sortkey(S1, (uint32_t)i);
      atomicAdd(&sm.p1.lh[k1 >> 21], 1u);
    }
    __syncthreads();
    for (int i = tid; i < HBINS; i += 256)
      if (sm.p1.lh[i]) atomicAdd(&hist[b * HBINS + i], sm.p1.lh[i]);
  }
  gbar(cnt_, gen_);

  // ---- P2 (blocks 0..63): rank candidates, scan hist, binary search ----
  if (blk < NB) {
    const int bb = blk;
    uint32_t nc = ald_u32(&ncand[bb]);
    const int M = nc < CANDCAP ? (int)nc : CANDCAP;
    for (int i = tid; i < M; i += 256) sm.p2.sc[i] = ald_u64(&cand[bb * CANDCAP + i]);
    for (int i = tid; i < HBINS; i += 256) sm.p2.sh[i] = ald_u32(&hist[bb * HBINS + i]);
    __syncthreads();
    // top-16 rank under (key2, idx); distinct pairs -> unique ranks
    for (int j = tid; j < M; j += 256) {
      u64 me = sm.p2.sc[j];
      int r = 0;
      for (int t = 0; t < M; ++t) r += (sm.p2.sc[t] < me) ? 1 : 0;
      if (r < NK) sm.p2.Rt[r] = (uint32_t)(me & 0xffffffffu);
    }
    // parallel inclusive scan of sh -> S (8 bins/thread + block scan)
    uint32_t loc[8]; uint32_t run = 0;
    for (int j = 0; j < 8; ++j) { run += sm.p2.sh[tid * 8 + j]; loc[j] = run; }
    sm.p2.ts[tid] = run;
    __syncthreads();
    for (int off = 1; off < 256; off <<= 1) {
      uint32_t v = (tid >= off) ? sm.p2.ts[tid - off] : 0u;
      __syncthreads();
      sm.p2.ts[tid] += v;
      __syncthreads();
    }
    uint32_t excl = sm.p2.ts[tid] - run;
    for (int j = 0; j < 8; ++j) sm.p2.S[tid * 8 + j] = excl + loc[j];
    __syncthreads();
    if (tid < NK) {
      uint32_t R = sm.p2.Rt[tid];
      int lo = 0, hi = HBINS - 1;
      while (lo < hi) {                      // smallest i with S[i] > R
        int mid = (lo + hi) >> 1;
        if (sm.p2.S[mid] > R) hi = mid; else lo = mid + 1;
      }
      ast_u32(&binsel[bb * NK + tid], (uint32_t)lo);
      ast_u32(&rem[bb * NK + tid], R - (lo ? sm.p2.S[lo - 1] : 0u));
    }
  }
  gbar(cnt_, gen_);

  // ---- P3: collect key1 elements landing in each target's bin ----
  if (tid < NK) sm.p3.bs[tid] = ald_u32(&binsel[b * NK + tid]);
  __syncthreads();
  {
    const int start = c * CHUNK;
    for (int i = start + tid; i < start + CHUNK; i += 256) {
      uint32_t k1 = sortkey(S1, (uint32_t)i);
      uint32_t pb = k1 >> 21;
      #pragma unroll
      for (int t = 0; t < NK; ++t) {
        if (pb == sm.p3.bs[t]) {
          uint32_t p = atomicAdd(&ncoll[b * NK + t], 1u);
          if (p < COLLCAP)
            ast_u64(&coll[(b * NK + t) * COLLCAP + p], ((u64)k1 << 32) | (uint32_t)i);
        }
      }
    }
  }
  gbar(cnt_, gen_);

  // ---- P4 (blocks 0..63): stable rank-select, gather cent, zero sums[0] ----
  if (blk < NB) {
    const int bb = blk;
    for (int i = tid; i < NK * COLLCAP; i += 256)
      sm.p4.lc[i] = ald_u64(&coll[bb * NK * COLLCAP + i]);
    __syncthreads();
    if (tid < NK) {
      uint32_t ncl = ald_u32(&ncoll[bb * NK + tid]);
      const int m = ncl < COLLCAP ? (int)ncl : COLLCAP;
      const uint32_t r = ald_u32(&rem[bb * NK + tid]);
      const u64* cc = &sm.p4.lc[tid * COLLCAP];
      u64 lo = 0ULL, cur = ~0ULL;
      bool first = true;
      for (uint32_t pass = 0; pass <= r; ++pass) {
        cur = ~0ULL;
        for (int i = 0; i < m; ++i) {
          u64 v = cc[i];
          if ((first || v > lo) && v < cur) cur = v;
        }
        lo = cur; first = false;
      }
      sm.p4.jsel[tid] = (int)(cur & 0xffffffffu);
    }
    __syncthreads();
    if (tid < NK * NCH) {
      int k = tid / NCH, ch = tid % NCH;
      ast_f32(&cent[bb * NK * NCH + tid],
              x[((size_t)bb * NPIX + (size_t)sm.p4.jsel[k]) * NCH + ch]);
    }
    if (tid < NK * 4) ast_f64(&sums[bb * NK * 4 + tid], 0.0);  // parity-0 buf
  }
  gbar(cnt_, gen_);

  // ---- P5: 10 k-means iterations, 1 barrier each ----
  // cs in LDS; sums triple-buffered f64 (zero target separated from its
  // readers/writers by >=1 barrier); every block computes the update
  // redundantly (deterministic: same f64 inputs -> same f32 result).
  if (tid < NK * NCH) sm.p5.cs[tid] = ald_f32(&cent[b * NK * NCH + tid]);
  __syncthreads();

  const float4* px4 = (const float4*)(x + (size_t)b * NPIX * NCH + (size_t)c * (CHUNK * NCH));

  for (int it = 0; it < NITER; ++it) {
    if (tid == 0) {
      int kn = -1;
      for (int k = 0; k < NK; ++k) {
        float a = sm.p5.cs[3 * k], bb2 = sm.p5.cs[3 * k + 1], cc2 = sm.p5.cs[3 * k + 2];
        if (a != a || bb2 != bb2 || cc2 != cc2) { kn = k; break; }
      }
      sm.p5.knan = kn;
    }
    sm.p5.acc[tid >> 6][tid & 63] = 0.0;
    if (tid < NK * 4)   // zero next-parity buffer (used after next barrier)
      ast_f64(&sums[((it + 1) % 3) * (NB * NK * 4) + b * NK * 4 + tid], 0.0);
    __syncthreads();

    float cr[NK * NCH];
    #pragma unroll
    for (int i = 0; i < NK * NCH; ++i) cr[i] = sm.p5.cs[i];
    const int kn = sm.p5.knan;
    double* a0 = sm.p5.acc[tid >> 6];

    for (int j = tid; j < NQUAD; j += 256) {
      const float4 A = px4[3 * j], Bv = px4[3 * j + 1], Cv = px4[3 * j + 2];
      const float qx[4][3] = {{A.x, A.y, A.z}, {A.w, Bv.x, Bv.y},
                              {Bv.z, Bv.w, Cv.x}, {Cv.y, Cv.z, Cv.w}};
      #pragma unroll
      for (int q = 0; q < 4; ++q) {
        const float v0 = qx[q][0], v1 = qx[q][1], v2 = qx[q][2];
        int best = 0;
        float bd = 3.402823466e38f;
        #pragma unroll
        for (int k = 0; k < NK; ++k) {   // numpy-exact: _rn chain, strict <
          float d0 = __fsub_rn(v0, cr[3 * k + 0]);
          float d1 = __fsub_rn(v1, cr[3 * k + 1]);
          float d2 = __fsub_rn(v2, cr[3 * k + 2]);
          float d = __fadd_rn(__fadd_rn(__fmul_rn(d0, d0), __fmul_rn(d1, d1)),
                              __fmul_rn(d2, d2));
          bool cnd = d < bd;
          bd = cnd ? d : bd;
          best = cnd ? k : best;
        }
        if (kn >= 0) best = kn;          // np.argmin: first NaN wins
        atomicAdd(&a0[best * 4 + 0], (double)v0);
        atomicAdd(&a0[best * 4 + 1], (double)v1);
        atomicAdd(&a0[best * 4 + 2], (double)v2);
        atomicAdd(&a0[best * 4 + 3], 1.0);
      }
    }
    __syncthreads();
    if (tid < NK * 4) {
      double v = sm.p5.acc[0][tid] + sm.p5.acc[1][tid] +
                 sm.p5.acc[2][tid] + sm.p5.acc[3][tid];
      atomicAdd(&sums[(it % 3) * (NB * NK * 4) + b * NK * 4 + tid], v);
    }
    gbar(cnt_, gen_);

    if (tid < NK * 4)
      sm.p5.raw[tid] = ald_f64(&sums[(it % 3) * (NB * NK * 4) + b * NK * 4 + tid]);
    __syncthreads();
    if (tid < NK * NCH) {
      int k = tid / NCH;
      float v = (float)(sm.p5.raw[k * 4 + (tid % NCH)] / sm.p5.raw[k * 4 + 3]);
      sm.p5.cs[tid] = v;                 // 0/0 -> NaN, matching reference
      if (it == NITER - 1 && c == 0) out[b * NK * NCH + tid] = v;
    }
    __syncthreads();
  }
}

// ---------------------------------------------------------------------------
// Fallback path (ws too small): R1-verified monolithic kinit + R2 loop.
// ---------------------------------------------------------------------------
__global__ __launch_bounds__(256) void kinit_mono(const float* __restrict__ x,
                                                  float* __restrict__ cent,
                                                  float* __restrict__ sums) {
  const int b = (int)blockIdx.x;
  const int tid = (int)threadIdx.x;
  __shared__ u64 cand[CANDCAP];
  __shared__ u64 coll[NK][COLLCAP];
  __shared__ uint32_t hist[HBINS];
  __shared__ uint32_t Rtgt[NK];
  __shared__ uint32_t binsel[NK];
  __shared__ uint32_t rem[NK];
  __shared__ int jsel[NK];
  __shared__ int ncand;
  __shared__ int ncoll[NK];
  KeyPair S1, S2;
  derive_keys(b, S1, S2);
  if (tid == 0) ncand = 0;
  if (tid < NK) ncoll[tid] = 0;
  for (int i = tid; i < HBINS; i += 256) hist[i] = 0u;
  __syncthreads();
  for (int i = tid; i < NPIX; i += 256) {
    uint32_t k2 = sortkey(S2, (uint32_t)i);
    if (k2 < T2VAL) {
      int p = atomicAdd(&ncand, 1);
      if (p < CANDCAP) cand[p] = ((u64)k2 << 32) | (uint32_t)i;
    }
    uint32_t k1 = sortkey(S1, (uint32_t)i);
    atomicAdd(&hist[k1 >> 21], 1u);
  }
  __syncthreads();
  const int M = ncand < CANDCAP ? ncand : CANDCAP;
  for (int j = tid; j < M; j += 256) {
    u64 me = cand[j];
    int rank = 0;
    for (int t = 0; t < M; ++t) rank += (cand[t] < me) ? 1 : 0;
    if (rank < NK) Rtgt[rank] = (uint32_t)(me & 0xffffffffu);
  }
  __syncthreads();
  if (tid < NK) {
    uint32_t R = Rtgt[tid], cum = 0u, bin = 0u;
    for (int i = 0; i < HBINS; ++i) {
      uint32_t h = hist[i];
      if (R < cum + h) { bin = (uint32_t)i; break; }
      cum += h;
    }
    binsel[tid] = bin;
    rem[tid] = R - cum;
  }
  __syncthreads();
  for (int i = tid; i < NPIX; i += 256) {
    uint32_t k1 = sortkey(S1, (uint32_t)i);
    uint32_t pb = k1 >> 21;
    #pragma unroll
    for (int t = 0; t < NK; ++t) {
      if (pb == binsel[t]) {
        int p = atomicAdd(&ncoll[t], 1);
        if (p < COLLCAP) coll[t][p] = ((u64)k1 << 32) | (uint32_t)i;
      }
    }
  }
  __syncthreads();
  if (tid < NK) {
    int m = ncoll[tid] < COLLCAP ? ncoll[tid] : COLLCAP;
    uint32_t r = rem[tid];
    u64 lo = 0ULL, cur = ~0ULL;
    bool first = true;
    for (uint32_t pass = 0; pass <= r; ++pass) {
      cur = ~0ULL;
      for (int t = 0; t < m; ++t) {
        u64 v = coll[tid][t];
        if ((first || v > lo) && v < cur) cur = v;
      }
      lo = cur; first = false;
    }
    jsel[tid] = (int)(cur & 0xffffffffu);
  }
  __syncthreads();
  if (tid < NK * NCH) {
    int k = tid / NCH, c = tid % NCH;
    cent[(b * NK + k) * NCH + c] = x[((size_t)b * NPIX + (size_t)jsel[k]) * NCH + c];
  }
  if (tid < NK * 4) sums[b * NK * 4 + tid] = 0.0f;
}

__global__ __launch_bounds__(256) void kassign(const float* __restrict__ x,
                                               const float* __restrict__ cent,
                                               float* __restrict__ sums) {
  const int b = (int)blockIdx.y;
  const int tid = (int)threadIdx.x;
  __shared__ float cs[NK * NCH];
  __shared__ float acc[4][NK * 4];
  __shared__ int knan_s;
  if (tid < NK * NCH) cs[tid] = cent[b * NK * NCH + tid];
  acc[tid >> 6][tid & 63] = 0.0f;
  __syncthreads();
  if (tid == 0) {
    int kn = -1;
    for (int k = 0; k < NK; ++k) {
      float a = cs[3 * k], bb = cs[3 * k + 1], cc = cs[3 * k + 2];
      if (a != a || bb != bb || cc != cc) { kn = k; break; }
    }
    knan_s = kn;
  }
  __syncthreads();
  float cr[NK * NCH];
  #pragma unroll
  for (int i = 0; i < NK * NCH; ++i) cr[i] = cs[i];
  const float* xb = x + (size_t)b * NPIX * NCH;
  const float4* p = (const float4*)(xb + (size_t)blockIdx.x * 3072);
  const float4 A = p[3 * tid], Bv = p[3 * tid + 1], Cv = p[3 * tid + 2];
  const float px[4][3] = {{A.x, A.y, A.z}, {A.w, Bv.x, Bv.y},
                          {Bv.z, Bv.w, Cv.x}, {Cv.y, Cv.z, Cv.w}};
  float* a0 = acc[tid >> 6];
  const int kn = knan_s;
  #pragma unroll
  for (int q = 0; q < 4; ++q) {
    const float v0 = px[q][0], v1 = px[q][1], v2 = px[q][2];
    int best = 0;
    float bd = 3.402823466e38f;
    #pragma unroll
    for (int k = 0; k < NK; ++k) {
      float d0 = __fsub_rn(v0, cr[3 * k + 0]);
      float d1 = __fsub_rn(v1, cr[3 * k + 1]);
      float d2 = __fsub_rn(v2, cr[3 * k + 2]);
      float d = __fadd_rn(__fadd_rn(__fmul_rn(d0, d0), __fmul_rn(d1, d1)),
                          __fmul_rn(d2, d2));
      bool cnd = d < bd;
      bd = cnd ? d : bd;
      best = cnd ? k : best;
    }
    if (kn >= 0) best = kn;
    atomicAdd(&a0[best * 4 + 0], v0);
    atomicAdd(&a0[best * 4 + 1], v1);
    atomicAdd(&a0[best * 4 + 2], v2);
    atomicAdd(&a0[best * 4 + 3], 1.0f);
  }
  __syncthreads();
  if (tid < NK * 4) {
    float v = acc[0][tid] + acc[1][tid] + acc[2][tid] + acc[3][tid];
    atomicAdd(&sums[b * NK * 4 + tid], v);
  }
}

__global__ __launch_bounds__(64) void kupdate(float* __restrict__ cent,
                                              float* __restrict__ sums,
                                              float* __restrict__ out) {
  const int b = (int)blockIdx.x;
  const int t = (int)threadIdx.x;
  float v = 0.0f;
  if (t < NK * NCH) {
    const int k = t / NCH, c = t % NCH;
    v = sums[b * NK * 4 + k * 4 + c] / sums[b * NK * 4 + k * 4 + 3];
  }
  __syncthreads();
  if (t < NK * NCH) {
    cent[b * NK * NCH + t] = v;
    out[b * NK * NCH + t] = v;
  }
  sums[b * NK * 4 + t] = 0.0f;
}

extern "C" void kernel_launch(void* const* d_in, const int* in_sizes, int n_in,
                              void* d_out, int out_size, void* d_ws, size_t ws_size,
                              hipStream_t stream) {
  (void)in_sizes; (void)n_in; (void)out_size;
  const float* x = (const float*)d_in[0];
  float* out = (float*)d_out;
  char* ws = (char*)d_ws;

  // ws layout (bytes)
  float*    cent   = (float*)(ws + 0);              // 12288
  double*   sums   = (double*)(ws + 12288);         // 98304 (3 parity bufs)
  uint32_t* ncand  = (uint32_t*)(ws + 110592);      // 256    } zero zone
  uint32_t* ncoll  = (uint32_t*)(ws + 110848);      // 4096   } 110592..
  uint32_t* bar    = (uint32_t*)(ws + 114944);      // 64     } ..639296
  uint32_t* hist   = (uint32_t*)(ws + 115008);      // 524288 }
  uint32_t* binsel = (uint32_t*)(ws + 639296);      // 4096
  uint32_t* rem    = (uint32_t*)(ws + 643392);      // 4096
  u64*      cand   = (u64*)(ws + 647488);           // 524288
  u64*      coll   = (u64*)(ws + 1171776);          // 1048576
  const size_t REQ = 2220352;

  if (ws_size >= REQ) {
    hipMemsetAsync(ws + 110592, 0, 528704, stream);
    mega<<<NBLK, 256, 0, stream>>>(x, out, cent, sums, ncand, ncoll, bar,
                                   hist, binsel, rem, cand, coll);
  } else {
    float* centf = (float*)ws;                 // fallback: f32 sums layout
    float* sumsf = centf + NB * NK * NCH;
    kinit_mono<<<NB, 256, 0, stream>>>(x, centf, sumsf);
    for (int it = 0; it < NITER; ++it) {
      kassign<<<dim3(49, NB), 256, 0, stream>>>(x, centf, sumsf);
      kupdate<<<NB, 64, 0, stream>>>(centf, sumsf, out);
    }
  }
}

// Round 4
// 1315.956 us; speedup vs baseline: 1.0331x; 1.0331x over previous
//
#include <hip/hip_runtime.h>
#include <stdint.h>

// ---------------------------------------------------------------------------
// ColorExtractor: per-image k-means (B=64, N=224*224, C=3, K=16, 10 iters).
// Threefry2x32 bit-exact (verified R1, absmax 0.0).
// R4: assign-loop accumulation via per-thread PRIVATE LDS columns
// (accf[64][256] f32, thread owns column tid; bank = tid%32 always ->
// conflict-free, atomic-free). R3's f64 LDS atomics caused 4.25e7
// bank-conflict cycles and 1332us. Cross-block: 64 f64 global atomics per
// block per iteration (low contention). Grid barrier structure from R3.
// ---------------------------------------------------------------------------

#define NB    64
#define NPIX  50176
#define NK    16
#define NCH   3
#define NITER 10
#define HBINS 2048
#define CANDCAP 1024     // expect ~320 cands/batch (T2VAL), huge margin
#define COLLCAP 128      // expect ~24.5/bin
#define NBLK  512        // 8 chunks x 64 batches; 2 blocks/CU on 256 CUs
#define CHUNK (NPIX / 8) // 6272 px per block-chunk
#define NQUADS (CHUNK / 4) // 1568 quads per block

typedef unsigned long long u64;

struct KeyPair { uint32_t a, b; };

__device__ __forceinline__ uint32_t rotl32(uint32_t v, uint32_t r) {
  return (v << r) | (v >> (32u - r));
}
__device__ __forceinline__ void tf_round(uint32_t& x0, uint32_t& x1, uint32_t r) {
  x0 += x1; x1 = rotl32(x1, r); x1 ^= x0;
}

// Threefry-2x32, 20 rounds, exactly as jax/_src/prng.py lowering.
__device__ __forceinline__ KeyPair threefry(uint32_t k0, uint32_t k1,
                                            uint32_t x0, uint32_t x1) {
  const uint32_t ks2 = k0 ^ k1 ^ 0x1BD11BDAu;
  x0 += k0; x1 += k1;
  tf_round(x0, x1, 13u); tf_round(x0, x1, 15u); tf_round(x0, x1, 26u); tf_round(x0, x1, 6u);
  x0 += k1;  x1 += ks2 + 1u;
  tf_round(x0, x1, 17u); tf_round(x0, x1, 29u); tf_round(x0, x1, 16u); tf_round(x0, x1, 24u);
  x0 += ks2; x1 += k0 + 2u;
  tf_round(x0, x1, 13u); tf_round(x0, x1, 15u); tf_round(x0, x1, 26u); tf_round(x0, x1, 6u);
  x0 += k0;  x1 += k1 + 3u;
  tf_round(x0, x1, 17u); tf_round(x0, x1, 29u); tf_round(x0, x1, 16u); tf_round(x0, x1, 24u);
  x0 += k1;  x1 += ks2 + 4u;
  tf_round(x0, x1, 13u); tf_round(x0, x1, 15u); tf_round(x0, x1, 26u); tf_round(x0, x1, 6u);
  x0 += ks2; x1 += k0 + 5u;
  KeyPair r; r.a = x0; r.b = x1; return r;
}

__device__ __forceinline__ uint32_t sortkey(KeyPair S, uint32_t i) {
  KeyPair r = threefry(S.a, S.b, 0u, i);   // counter = 64-bit iota (hi=0,lo=i)
  return r.a ^ r.b;                        // 32-bit path XOR-folds the block
}

__device__ __forceinline__ void derive_keys(int b, KeyPair& S1, KeyPair& S2) {
  KeyPair root; root.a = 0u; root.b = 42u;
  KeyPair kb = threefry(root.a, root.b, 0u, (uint32_t)b);   // foldlike split
  KeyPair K1 = threefry(kb.a, kb.b, 0u, 0u);
  S1 = threefry(kb.a, kb.b, 0u, 1u);                        // round-1 subkey
  S2 = threefry(K1.a, K1.b, 0u, 1u);                        // round-2 subkey
}

#define T2VAL 27394240u  // ~2^32*320/NPIX

// ---- agent-scope (cross-XCD coherent) accessors ---------------------------
__device__ __forceinline__ void ast_u64(u64* p, u64 v) {
  __hip_atomic_store(p, v, __ATOMIC_RELAXED, __HIP_MEMORY_SCOPE_AGENT);
}
__device__ __forceinline__ u64 ald_u64(const u64* p) {
  return __hip_atomic_load(p, __ATOMIC_RELAXED, __HIP_MEMORY_SCOPE_AGENT);
}
__device__ __forceinline__ void ast_u32(uint32_t* p, uint32_t v) {
  __hip_atomic_store(p, v, __ATOMIC_RELAXED, __HIP_MEMORY_SCOPE_AGENT);
}
__device__ __forceinline__ uint32_t ald_u32(const uint32_t* p) {
  return __hip_atomic_load(p, __ATOMIC_RELAXED, __HIP_MEMORY_SCOPE_AGENT);
}
__device__ __forceinline__ void ast_f32(float* p, float v) {
  __hip_atomic_store(p, v, __ATOMIC_RELAXED, __HIP_MEMORY_SCOPE_AGENT);
}
__device__ __forceinline__ float ald_f32(const float* p) {
  return __hip_atomic_load(p, __ATOMIC_RELAXED, __HIP_MEMORY_SCOPE_AGENT);
}
__device__ __forceinline__ void ast_f64(double* p, double v) {
  __hip_atomic_store(p, v, __ATOMIC_RELAXED, __HIP_MEMORY_SCOPE_AGENT);
}
__device__ __forceinline__ double ald_f64(const double* p) {
  return __hip_atomic_load(p, __ATOMIC_RELAXED, __HIP_MEMORY_SCOPE_AGENT);
}

// Grid barrier: counter + generation, agent scope (verified R3, absmax 0.0).
__device__ __forceinline__ void gbar(uint32_t* cnt, uint32_t* gen) {
  __syncthreads();
  if (threadIdx.x == 0) {
    uint32_t g = __hip_atomic_load(gen, __ATOMIC_RELAXED, __HIP_MEMORY_SCOPE_AGENT);
    uint32_t old = __hip_atomic_fetch_add(cnt, 1u, __ATOMIC_ACQ_REL,
                                          __HIP_MEMORY_SCOPE_AGENT);
    if (old == (uint32_t)NBLK - 1u) {
      __hip_atomic_store(cnt, 0u, __ATOMIC_RELAXED, __HIP_MEMORY_SCOPE_AGENT);
      __hip_atomic_fetch_add(gen, 1u, __ATOMIC_RELEASE, __HIP_MEMORY_SCOPE_AGENT);
    } else {
      while (__hip_atomic_load(gen, __ATOMIC_ACQUIRE,
                               __HIP_MEMORY_SCOPE_AGENT) == g)
        __builtin_amdgcn_s_sleep(1);
    }
  }
  __syncthreads();
}

union SMem {
  struct { uint32_t lh[HBINS]; } p1;
  struct { u64 sc[CANDCAP]; uint32_t sh[HBINS]; uint32_t S[HBINS];
           uint32_t ts[256]; uint32_t Rt[NK]; } p2;
  struct { uint32_t bs[NK]; } p3;
  struct { u64 lc[NK * COLLCAP]; int jsel[NK]; } p4;
  // Exactly 64 KB: row r = cluster*4+{c0,c1,c2,cnt}, column = tid (private).
  struct { float accf[64 * 256]; } p5;
};

__global__ __launch_bounds__(256, 2) void mega(
    const float* __restrict__ x, float* __restrict__ out,
    float* __restrict__ cent, double* __restrict__ sums,
    uint32_t* __restrict__ ncand, uint32_t* __restrict__ ncoll,
    uint32_t* __restrict__ bar, uint32_t* __restrict__ hist,
    uint32_t* __restrict__ binsel, uint32_t* __restrict__ rem,
    u64* __restrict__ cand, u64* __restrict__ coll) {
  __shared__ SMem sm;
  const int blk = (int)blockIdx.x;
  const int tid = (int)threadIdx.x;
  const int b = blk >> 3;        // batch
  const int c = blk & 7;         // chunk within batch
  uint32_t* cnt_ = bar;
  uint32_t* gen_ = bar + 1;

  KeyPair S1, S2;
  derive_keys(b, S1, S2);

  // ---- P1: key2 candidate filter + key1 prefix histogram ----
  for (int i = tid; i < HBINS; i += 256) sm.p1.lh[i] = 0u;
  __syncthreads();
  {
    const int start = c * CHUNK;
    for (int i = start + tid; i < start + CHUNK; i += 256) {
      uint32_t k2 = sortkey(S2, (uint32_t)i);
      if (k2 < T2VAL) {
        uint32_t p = atomicAdd(&ncand[b], 1u);
        if (p < CANDCAP) ast_u64(&cand[b * CANDCAP + p], ((u64)k2 << 32) | (uint32_t)i);
      }
      uint32_t k1 = sortkey(S1, (uint32_t)i);
      atomicAdd(&sm.p1.lh[k1 >> 21], 1u);
    }
    __syncthreads();
    for (int i = tid; i < HBINS; i += 256)
      if (sm.p1.lh[i]) atomicAdd(&hist[b * HBINS + i], sm.p1.lh[i]);
  }
  gbar(cnt_, gen_);

  // ---- P2 (blocks 0..63): rank candidates, scan hist, binary search ----
  if (blk < NB) {
    const int bb = blk;
    uint32_t nc = ald_u32(&ncand[bb]);
    const int M = nc < CANDCAP ? (int)nc : CANDCAP;
    for (int i = tid; i < M; i += 256) sm.p2.sc[i] = ald_u64(&cand[bb * CANDCAP + i]);
    for (int i = tid; i < HBINS; i += 256) sm.p2.sh[i] = ald_u32(&hist[bb * HBINS + i]);
    __syncthreads();
    // top-16 rank under (key2, idx); distinct pairs -> unique ranks
    for (int j = tid; j < M; j += 256) {
      u64 me = sm.p2.sc[j];
      int r = 0;
      for (int t = 0; t < M; ++t) r += (sm.p2.sc[t] < me) ? 1 : 0;
      if (r < NK) sm.p2.Rt[r] = (uint32_t)(me & 0xffffffffu);
    }
    // parallel inclusive scan of sh -> S (8 bins/thread + block scan)
    uint32_t loc[8]; uint32_t run = 0;
    for (int j = 0; j < 8; ++j) { run += sm.p2.sh[tid * 8 + j]; loc[j] = run; }
    sm.p2.ts[tid] = run;
    __syncthreads();
    for (int off = 1; off < 256; off <<= 1) {
      uint32_t v = (tid >= off) ? sm.p2.ts[tid - off] : 0u;
      __syncthreads();
      sm.p2.ts[tid] += v;
      __syncthreads();
    }
    uint32_t excl = sm.p2.ts[tid] - run;
    for (int j = 0; j < 8; ++j) sm.p2.S[tid * 8 + j] = excl + loc[j];
    __syncthreads();
    if (tid < NK) {
      uint32_t R = sm.p2.Rt[tid];
      int lo = 0, hi = HBINS - 1;
      while (lo < hi) {                      // smallest i with S[i] > R
        int mid = (lo + hi) >> 1;
        if (sm.p2.S[mid] > R) hi = mid; else lo = mid + 1;
      }
      ast_u32(&binsel[bb * NK + tid], (uint32_t)lo);
      ast_u32(&rem[bb * NK + tid], R - (lo ? sm.p2.S[lo - 1] : 0u));
    }
  }
  gbar(cnt_, gen_);

  // ---- P3: collect key1 elements landing in each target's bin ----
  {
    __shared__ uint32_t bs_s[NK];
    if (tid < NK) bs_s[tid] = ald_u32(&binsel[b * NK + tid]);
    __syncthreads();
    const int start = c * CHUNK;
    for (int i = start + tid; i < start + CHUNK; i += 256) {
      uint32_t k1 = sortkey(S1, (uint32_t)i);
      uint32_t pb = k1 >> 21;
      #pragma unroll
      for (int t = 0; t < NK; ++t) {
        if (pb == bs_s[t]) {
          uint32_t p = atomicAdd(&ncoll[b * NK + t], 1u);
          if (p < COLLCAP)
            ast_u64(&coll[(b * NK + t) * COLLCAP + p], ((u64)k1 << 32) | (uint32_t)i);
        }
      }
    }
  }
  gbar(cnt_, gen_);

  // ---- P4 (blocks 0..63): stable rank-select, gather cent, zero sums[0] ----
  if (blk < NB) {
    const int bb = blk;
    for (int i = tid; i < NK * COLLCAP; i += 256)
      sm.p4.lc[i] = ald_u64(&coll[bb * NK * COLLCAP + i]);
    __syncthreads();
    if (tid < NK) {
      uint32_t ncl = ald_u32(&ncoll[bb * NK + tid]);
      const int m = ncl < COLLCAP ? (int)ncl : COLLCAP;
      const uint32_t r = ald_u32(&rem[bb * NK + tid]);
      const u64* cc = &sm.p4.lc[tid * COLLCAP];
      u64 lo = 0ULL, cur = ~0ULL;
      bool first = true;
      for (uint32_t pass = 0; pass <= r; ++pass) {
        cur = ~0ULL;
        for (int i = 0; i < m; ++i) {
          u64 v = cc[i];
          if ((first || v > lo) && v < cur) cur = v;
        }
        lo = cur; first = false;
      }
      sm.p4.jsel[tid] = (int)(cur & 0xffffffffu);
    }
    __syncthreads();
    if (tid < NK * NCH) {
      int k = tid / NCH, ch = tid % NCH;
      ast_f32(&cent[bb * NK * NCH + tid],
              x[((size_t)bb * NPIX + (size_t)sm.p4.jsel[k]) * NCH + ch]);
    }
    if (tid < NK * 4) ast_f64(&sums[bb * NK * 4 + tid], 0.0);  // parity-0 buf
  }
  gbar(cnt_, gen_);

  // ---- P5: 10 k-means iterations, 1 barrier each ----
  // accf[64][256] f32: thread tid owns column tid (no atomics, bank=tid%32
  // always -> conflict-free). Triple-buffered f64 global sums across blocks.
  const float4* px4 = (const float4*)(x + (size_t)b * NPIX * NCH + (size_t)c * (CHUNK * NCH));
  float* accf = sm.p5.accf;

  for (int it = 0; it < NITER; ++it) {
    // (1) update phase: new centroids -> accf[0..47] scratch
    if (tid < NK * NCH) {
      float v;
      if (it == 0) {
        v = ald_f32(&cent[b * NK * NCH + tid]);
      } else {
        const int k = tid / NCH, ch = tid - k * NCH;
        const double* sb = &sums[((it - 1) % 3) * (NB * NK * 4) + b * NK * 4];
        double s = ald_f64(&sb[k * 4 + ch]);
        double n = ald_f64(&sb[k * 4 + 3]);
        v = (float)(s / n);                  // 0/0 -> NaN, matching reference
      }
      accf[tid] = v;
    }
    __syncthreads();
    // (2) broadcast to registers; knan per-thread (batch-uniform result)
    float cr[NK * NCH];
    {
      const float4* cp = (const float4*)accf;
      #pragma unroll
      for (int i = 0; i < 12; ++i) {
        float4 t4 = cp[i];
        cr[4 * i + 0] = t4.x; cr[4 * i + 1] = t4.y;
        cr[4 * i + 2] = t4.z; cr[4 * i + 3] = t4.w;
      }
    }
    int kn = -1;
    #pragma unroll
    for (int k = NK - 1; k >= 0; --k) {      // descending so lowest k wins
      float a = cr[3 * k], bb2 = cr[3 * k + 1], cc2 = cr[3 * k + 2];
      if (a != a || bb2 != bb2 || cc2 != cc2) kn = k;
    }
    __syncthreads();
    // (3) zero accf + next-parity global buffer
    {
      float4 z4 = make_float4(0.f, 0.f, 0.f, 0.f);
      float4* zp = (float4*)accf;
      #pragma unroll
      for (int i = 0; i < 16; ++i) zp[tid + 256 * i] = z4;
      if (tid < NK * 4)
        ast_f64(&sums[((it + 1) % 3) * (NB * NK * 4) + b * NK * 4 + tid], 0.0);
    }
    __syncthreads();
    // (4) pixel loop: numpy-exact distances + argmin, private-column RMW
    float* a0 = &accf[tid];
    for (int j = tid; j < NQUADS; j += 256) {
      const float4 A = px4[3 * j], Bv = px4[3 * j + 1], Cv = px4[3 * j + 2];
      const float qx[4][3] = {{A.x, A.y, A.z}, {A.w, Bv.x, Bv.y},
                              {Bv.z, Bv.w, Cv.x}, {Cv.y, Cv.z, Cv.w}};
      #pragma unroll
      for (int q = 0; q < 4; ++q) {
        const float v0 = qx[q][0], v1 = qx[q][1], v2 = qx[q][2];
        int best = 0;
        float bd = 3.402823466e38f;
        #pragma unroll
        for (int k = 0; k < NK; ++k) {   // _rn chain, strict <, ascending k
          float d0 = __fsub_rn(v0, cr[3 * k + 0]);
          float d1 = __fsub_rn(v1, cr[3 * k + 1]);
          float d2 = __fsub_rn(v2, cr[3 * k + 2]);
          float d = __fadd_rn(__fadd_rn(__fmul_rn(d0, d0), __fmul_rn(d1, d1)),
                              __fmul_rn(d2, d2));
          bool cnd = d < bd;
          bd = cnd ? d : bd;
          best = cnd ? k : best;
        }
        if (kn >= 0) best = kn;          // np.argmin: first NaN wins
        const int r = best << 10;        // (best*4)*256 floats
        a0[r]       += v0;
        a0[r + 256] += v1;
        a0[r + 512] += v2;
        a0[r + 768] += 1.0f;
      }
    }
    __syncthreads();
    // (5) reduce: thread (r=tid&63, q=tid>>6) sums its 64-col row segment
    double part = 0.0;
    {
      const int r = tid & 63, q = tid >> 6;
      const float4* rp = (const float4*)&accf[r * 256 + q * 64];
      #pragma unroll
      for (int m = 0; m < 16; ++m) {
        float4 t4 = rp[m];
        part += (double)t4.x + (double)t4.y + (double)t4.z + (double)t4.w;
      }
    }
    __syncthreads();
    {
      double* red = (double*)accf;       // reuse rows 0-1 as f64 scratch
      red[tid] = part;
      __syncthreads();
      if (tid < 64) {
        double tot = red[tid] + red[64 + tid] + red[128 + tid] + red[192 + tid];
        atomicAdd(&sums[(it % 3) * (NB * NK * 4) + b * NK * 4 + tid], tot);
      }
    }
    gbar(cnt_, gen_);
  }

  // final centroids -> out (chunk-0 blocks write)
  if (c == 0 && tid < NK * NCH) {
    const int k = tid / NCH, ch = tid - k * NCH;
    const double* sb = &sums[((NITER - 1) % 3) * (NB * NK * 4) + b * NK * 4];
    double s = ald_f64(&sb[k * 4 + ch]);
    double n = ald_f64(&sb[k * 4 + 3]);
    out[b * NK * NCH + tid] = (float)(s / n);
  }
}

// ---------------------------------------------------------------------------
// Fallback path (ws too small): R1-verified monolithic kinit + R2 loop.
// ---------------------------------------------------------------------------
__global__ __launch_bounds__(256) void kinit_mono(const float* __restrict__ x,
                                                  float* __restrict__ cent,
                                                  float* __restrict__ sums) {
  const int b = (int)blockIdx.x;
  const int tid = (int)threadIdx.x;
  __shared__ u64 cand[CANDCAP];
  __shared__ u64 coll[NK][COLLCAP];
  __shared__ uint32_t hist[HBINS];
  __shared__ uint32_t Rtgt[NK];
  __shared__ uint32_t binsel[NK];
  __shared__ uint32_t rem[NK];
  __shared__ int jsel[NK];
  __shared__ int ncand;
  __shared__ int ncoll[NK];
  KeyPair S1, S2;
  derive_keys(b, S1, S2);
  if (tid == 0) ncand = 0;
  if (tid < NK) ncoll[tid] = 0;
  for (int i = tid; i < HBINS; i += 256) hist[i] = 0u;
  __syncthreads();
  for (int i = tid; i < NPIX; i += 256) {
    uint32_t k2 = sortkey(S2, (uint32_t)i);
    if (k2 < T2VAL) {
      int p = atomicAdd(&ncand, 1);
      if (p < CANDCAP) cand[p] = ((u64)k2 << 32) | (uint32_t)i;
    }
    uint32_t k1 = sortkey(S1, (uint32_t)i);
    atomicAdd(&hist[k1 >> 21], 1u);
  }
  __syncthreads();
  const int M = ncand < CANDCAP ? ncand : CANDCAP;
  for (int j = tid; j < M; j += 256) {
    u64 me = cand[j];
    int rank = 0;
    for (int t = 0; t < M; ++t) rank += (cand[t] < me) ? 1 : 0;
    if (rank < NK) Rtgt[rank] = (uint32_t)(me & 0xffffffffu);
  }
  __syncthreads();
  if (tid < NK) {
    uint32_t R = Rtgt[tid], cum = 0u, bin = 0u;
    for (int i = 0; i < HBINS; ++i) {
      uint32_t h = hist[i];
      if (R < cum + h) { bin = (uint32_t)i; break; }
      cum += h;
    }
    binsel[tid] = bin;
    rem[tid] = R - cum;
  }
  __syncthreads();
  for (int i = tid; i < NPIX; i += 256) {
    uint32_t k1 = sortkey(S1, (uint32_t)i);
    uint32_t pb = k1 >> 21;
    #pragma unroll
    for (int t = 0; t < NK; ++t) {
      if (pb == binsel[t]) {
        int p = atomicAdd(&ncoll[t], 1);
        if (p < COLLCAP) coll[t][p] = ((u64)k1 << 32) | (uint32_t)i;
      }
    }
  }
  __syncthreads();
  if (tid < NK) {
    int m = ncoll[tid] < COLLCAP ? ncoll[tid] : COLLCAP;
    uint32_t r = rem[tid];
    u64 lo = 0ULL, cur = ~0ULL;
    bool first = true;
    for (uint32_t pass = 0; pass <= r; ++pass) {
      cur = ~0ULL;
      for (int t = 0; t < m; ++t) {
        u64 v = coll[tid][t];
        if ((first || v > lo) && v < cur) cur = v;
      }
      lo = cur; first = false;
    }
    jsel[tid] = (int)(cur & 0xffffffffu);
  }
  __syncthreads();
  if (tid < NK * NCH) {
    int k = tid / NCH, c = tid % NCH;
    cent[(b * NK + k) * NCH + c] = x[((size_t)b * NPIX + (size_t)jsel[k]) * NCH + c];
  }
  if (tid < NK * 4) sums[b * NK * 4 + tid] = 0.0f;
}

__global__ __launch_bounds__(256) void kassign(const float* __restrict__ x,
                                               const float* __restrict__ cent,
                                               float* __restrict__ sums) {
  const int b = (int)blockIdx.y;
  const int tid = (int)threadIdx.x;
  __shared__ float cs[NK * NCH];
  __shared__ float acc[4][NK * 4];
  __shared__ int knan_s;
  if (tid < NK * NCH) cs[tid] = cent[b * NK * NCH + tid];
  acc[tid >> 6][tid & 63] = 0.0f;
  __syncthreads();
  if (tid == 0) {
    int kn = -1;
    for (int k = 0; k < NK; ++k) {
      float a = cs[3 * k], bb = cs[3 * k + 1], cc = cs[3 * k + 2];
      if (a != a || bb != bb || cc != cc) { kn = k; break; }
    }
    knan_s = kn;
  }
  __syncthreads();
  float cr[NK * NCH];
  #pragma unroll
  for (int i = 0; i < NK * NCH; ++i) cr[i] = cs[i];
  const float* xb = x + (size_t)b * NPIX * NCH;
  const float4* p = (const float4*)(xb + (size_t)blockIdx.x * 3072);
  const float4 A = p[3 * tid], Bv = p[3 * tid + 1], Cv = p[3 * tid + 2];
  const float px[4][3] = {{A.x, A.y, A.z}, {A.w, Bv.x, Bv.y},
                          {Bv.z, Bv.w, Cv.x}, {Cv.y, Cv.z, Cv.w}};
  float* a0 = acc[tid >> 6];
  const int kn = knan_s;
  #pragma unroll
  for (int q = 0; q < 4; ++q) {
    const float v0 = px[q][0], v1 = px[q][1], v2 = px[q][2];
    int best = 0;
    float bd = 3.402823466e38f;
    #pragma unroll
    for (int k = 0; k < NK; ++k) {
      float d0 = __fsub_rn(v0, cr[3 * k + 0]);
      float d1 = __fsub_rn(v1, cr[3 * k + 1]);
      float d2 = __fsub_rn(v2, cr[3 * k + 2]);
      float d = __fadd_rn(__fadd_rn(__fmul_rn(d0, d0), __fmul_rn(d1, d1)),
                          __fmul_rn(d2, d2));
      bool cnd = d < bd;
      bd = cnd ? d : bd;
      best = cnd ? k : best;
    }
    if (kn >= 0) best = kn;
    atomicAdd(&a0[best * 4 + 0], v0);
    atomicAdd(&a0[best * 4 + 1], v1);
    atomicAdd(&a0[best * 4 + 2], v2);
    atomicAdd(&a0[best * 4 + 3], 1.0f);
  }
  __syncthreads();
  if (tid < NK * 4) {
    float v = acc[0][tid] + acc[1][tid] + acc[2][tid] + acc[3][tid];
    atomicAdd(&sums[b * NK * 4 + tid], v);
  }
}

__global__ __launch_bounds__(64) void kupdate(float* __restrict__ cent,
                                              float* __restrict__ sums,
                                              float* __restrict__ out) {
  const int b = (int)blockIdx.x;
  const int t = (int)threadIdx.x;
  float v = 0.0f;
  if (t < NK * NCH) {
    const int k = t / NCH, c = t % NCH;
    v = sums[b * NK * 4 + k * 4 + c] / sums[b * NK * 4 + k * 4 + 3];
  }
  __syncthreads();
  if (t < NK * NCH) {
    cent[b * NK * NCH + t] = v;
    out[b * NK * NCH + t] = v;
  }
  sums[b * NK * 4 + t] = 0.0f;
}

extern "C" void kernel_launch(void* const* d_in, const int* in_sizes, int n_in,
                              void* d_out, int out_size, void* d_ws, size_t ws_size,
                              hipStream_t stream) {
  (void)in_sizes; (void)n_in; (void)out_size;
  const float* x = (const float*)d_in[0];
  float* out = (float*)d_out;
  char* ws = (char*)d_ws;

  // ws layout (bytes)
  float*    cent   = (float*)(ws + 0);              // 12288
  double*   sums   = (double*)(ws + 12288);         // 98304 (3 parity bufs)
  uint32_t* ncand  = (uint32_t*)(ws + 110592);      // 256    } zero zone
  uint32_t* ncoll  = (uint32_t*)(ws + 110848);      // 4096   } 110592..
  uint32_t* bar    = (uint32_t*)(ws + 114944);      // 64     } ..639296
  uint32_t* hist   = (uint32_t*)(ws + 115008);      // 524288 }
  uint32_t* binsel = (uint32_t*)(ws + 639296);      // 4096
  uint32_t* rem    = (uint32_t*)(ws + 643392);      // 4096
  u64*      cand   = (u64*)(ws + 647488);           // 524288
  u64*      coll   = (u64*)(ws + 1171776);          // 1048576
  const size_t REQ = 2220352;

  if (ws_size >= REQ) {
    hipMemsetAsync(ws + 110592, 0, 528704, stream);
    mega<<<NBLK, 256, 0, stream>>>(x, out, cent, sums, ncand, ncoll, bar,
                                   hist, binsel, rem, cand, coll);
  } else {
    float* centf = (float*)ws;                 // fallback: f32 sums layout
    float* sumsf = centf + NB * NK * NCH;
    kinit_mono<<<NB, 256, 0, stream>>>(x, centf, sumsf);
    for (int it = 0; it < NITER; ++it) {
      kassign<<<dim3(49, NB), 256, 0, stream>>>(x, centf, sumsf);
      kupdate<<<NB, 64, 0, stream>>>(centf, sumsf, out);
    }
  }
}

// Round 5
// 687.990 us; speedup vs baseline: 1.9760x; 1.9128x over previous
//
#include <hip/hip_runtime.h>
#include <stdint.h>

// ---------------------------------------------------------------------------
// ColorExtractor: per-image k-means (B=64, H*W=50176, C=3, K=16, 10 iters).
// Threefry2x32 bit-exact (verified R1, absmax 0.0).
// R5: FIX THE GRID BARRIER. R3/R4's gbar polled with agent-scope ACQUIRE
// loads -> each poll invalidates the XCD's L2 (gfx950 L2s not cross-coherent,
// acquire@agent = L1+L2 inv). 511 spinning blocks = continuous L2-invalidate
// storm: FETCH_SIZE was 3.6x input, VALUBusy 11%, dur insensitive to inner
// loop. New gbar: relaxed spin + ONE acquire fence on exit, release fence on
// arrival, tree arrival (8 groups x 64) to kill same-line RMW serialization.
// Cross-block data now uses plain loads/stores ordered by the gbar fences.
// ---------------------------------------------------------------------------

#define NB    64
#define NPIX  50176
#define NK    16
#define NCH   3
#define NITER 10
#define HBINS 2048
#define CANDCAP 1024     // expect ~320 cands/batch (T2VAL), huge margin
#define COLLCAP 128      // expect ~24.5/bin
#define NBLK  512        // 8 chunks x 64 batches; 2 blocks/CU on 256 CUs
#define NGRP  8
#define GRPSZ (NBLK / NGRP)
#define CHUNK (NPIX / 8) // 6272 px per block-chunk
#define NQUADS (CHUNK / 4)

typedef unsigned long long u64;

struct KeyPair { uint32_t a, b; };

__device__ __forceinline__ uint32_t rotl32(uint32_t v, uint32_t r) {
  return (v << r) | (v >> (32u - r));
}
__device__ __forceinline__ void tf_round(uint32_t& x0, uint32_t& x1, uint32_t r) {
  x0 += x1; x1 = rotl32(x1, r); x1 ^= x0;
}

// Threefry-2x32, 20 rounds, exactly as jax/_src/prng.py lowering.
__device__ __forceinline__ KeyPair threefry(uint32_t k0, uint32_t k1,
                                            uint32_t x0, uint32_t x1) {
  const uint32_t ks2 = k0 ^ k1 ^ 0x1BD11BDAu;
  x0 += k0; x1 += k1;
  tf_round(x0, x1, 13u); tf_round(x0, x1, 15u); tf_round(x0, x1, 26u); tf_round(x0, x1, 6u);
  x0 += k1;  x1 += ks2 + 1u;
  tf_round(x0, x1, 17u); tf_round(x0, x1, 29u); tf_round(x0, x1, 16u); tf_round(x0, x1, 24u);
  x0 += ks2; x1 += k0 + 2u;
  tf_round(x0, x1, 13u); tf_round(x0, x1, 15u); tf_round(x0, x1, 26u); tf_round(x0, x1, 6u);
  x0 += k0;  x1 += k1 + 3u;
  tf_round(x0, x1, 17u); tf_round(x0, x1, 29u); tf_round(x0, x1, 16u); tf_round(x0, x1, 24u);
  x0 += k1;  x1 += ks2 + 4u;
  tf_round(x0, x1, 13u); tf_round(x0, x1, 15u); tf_round(x0, x1, 26u); tf_round(x0, x1, 6u);
  x0 += ks2; x1 += k0 + 5u;
  KeyPair r; r.a = x0; r.b = x1; return r;
}

__device__ __forceinline__ uint32_t sortkey(KeyPair S, uint32_t i) {
  KeyPair r = threefry(S.a, S.b, 0u, i);   // counter = 64-bit iota (hi=0,lo=i)
  return r.a ^ r.b;                        // 32-bit path XOR-folds the block
}

__device__ __forceinline__ void derive_keys(int b, KeyPair& S1, KeyPair& S2) {
  KeyPair root; root.a = 0u; root.b = 42u;
  KeyPair kb = threefry(root.a, root.b, 0u, (uint32_t)b);   // foldlike split
  KeyPair K1 = threefry(kb.a, kb.b, 0u, 0u);
  S1 = threefry(kb.a, kb.b, 0u, 1u);                        // round-1 subkey
  S2 = threefry(K1.a, K1.b, 0u, 1u);                        // round-2 subkey
}

#define T2VAL 27394240u  // ~2^32*320/NPIX

// uniform-address cross-block read: atomic so it can't be scalar-cached
__device__ __forceinline__ uint32_t ald_u32(const uint32_t* p) {
  return __hip_atomic_load(p, __ATOMIC_RELAXED, __HIP_MEMORY_SCOPE_AGENT);
}

// Grid barrier, R5: relaxed spin + single acquire fence; tree arrival.
// bar layout (u32 idx): [g*16] group counters g=0..7 (64B apart),
// [128] root, [144] gen.
__device__ __forceinline__ void gbar(uint32_t* bar, int blk) {
  __syncthreads();
  if (threadIdx.x == 0) {
    uint32_t* grp  = bar + ((blk & (NGRP - 1)) << 4);
    uint32_t* root = bar + 128;
    uint32_t* gen  = bar + 144;
    uint32_t g = __hip_atomic_load(gen, __ATOMIC_RELAXED, __HIP_MEMORY_SCOPE_AGENT);
    __builtin_amdgcn_fence(__ATOMIC_RELEASE, "agent");  // publish our writes
    uint32_t a = __hip_atomic_fetch_add(grp, 1u, __ATOMIC_ACQ_REL,
                                        __HIP_MEMORY_SCOPE_AGENT);
    if (a == (uint32_t)GRPSZ - 1u) {
      __hip_atomic_store(grp, 0u, __ATOMIC_RELAXED, __HIP_MEMORY_SCOPE_AGENT);
      uint32_t r = __hip_atomic_fetch_add(root, 1u, __ATOMIC_ACQ_REL,
                                          __HIP_MEMORY_SCOPE_AGENT);
      if (r == (uint32_t)NGRP - 1u) {
        __hip_atomic_store(root, 0u, __ATOMIC_RELAXED, __HIP_MEMORY_SCOPE_AGENT);
        __hip_atomic_store(gen, g + 1u, __ATOMIC_RELEASE, __HIP_MEMORY_SCOPE_AGENT);
      } else {
        while (__hip_atomic_load(gen, __ATOMIC_RELAXED,
                                 __HIP_MEMORY_SCOPE_AGENT) == g)
          __builtin_amdgcn_s_sleep(1);
      }
    } else {
      while (__hip_atomic_load(gen, __ATOMIC_RELAXED,
                               __HIP_MEMORY_SCOPE_AGENT) == g)
        __builtin_amdgcn_s_sleep(1);
    }
    __builtin_amdgcn_fence(__ATOMIC_ACQUIRE, "agent");  // one L1/L2 inv total
  }
  __syncthreads();
}

union SMem {
  struct { uint32_t lh[HBINS]; } p1;
  struct { u64 sc[CANDCAP]; uint32_t sh[HBINS]; uint32_t S[HBINS];
           uint32_t ts[256]; uint32_t Rt[NK]; } p2;
  struct { uint32_t bs[NK]; } p3;
  struct { u64 lc[NK * COLLCAP]; int jsel[NK]; } p4;
  // 64 KB: row r = cluster*4+{c0,c1,c2,cnt}, column = tid (private -> no
  // atomics; bank = tid%32 always -> conflict-free).
  struct { float accf[64 * 256]; } p5;
};

__global__ __launch_bounds__(256, 2) void mega(
    const float* __restrict__ x, float* __restrict__ out,
    float* __restrict__ cent, double* __restrict__ sums,
    uint32_t* __restrict__ ncand, uint32_t* __restrict__ ncoll,
    uint32_t* __restrict__ bar, uint32_t* __restrict__ hist,
    uint32_t* __restrict__ binsel, uint32_t* __restrict__ rem,
    u64* __restrict__ cand, u64* __restrict__ coll) {
  __shared__ SMem sm;
  const int blk = (int)blockIdx.x;
  const int tid = (int)threadIdx.x;
  const int b = blk >> 3;        // batch
  const int c = blk & 7;         // chunk within batch

  KeyPair S1, S2;
  derive_keys(b, S1, S2);

  // ---- P1: key2 candidate filter + key1 prefix histogram ----
  for (int i = tid; i < HBINS; i += 256) sm.p1.lh[i] = 0u;
  __syncthreads();
  {
    const int start = c * CHUNK;
    for (int i = start + tid; i < start + CHUNK; i += 256) {
      uint32_t k2 = sortkey(S2, (uint32_t)i);
      if (k2 < T2VAL) {
        uint32_t p = atomicAdd(&ncand[b], 1u);
        if (p < CANDCAP) cand[b * CANDCAP + p] = ((u64)k2 << 32) | (uint32_t)i;
      }
      uint32_t k1 = sortkey(S1, (uint32_t)i);
      atomicAdd(&sm.p1.lh[k1 >> 21], 1u);
    }
    __syncthreads();
    for (int i = tid; i < HBINS; i += 256)
      if (sm.p1.lh[i]) atomicAdd(&hist[b * HBINS + i], sm.p1.lh[i]);
  }
  gbar(bar, blk);

  // ---- P2 (blocks 0..63): rank candidates, scan hist, binary search ----
  if (blk < NB) {
    const int bb = blk;
    uint32_t nc = ald_u32(&ncand[bb]);   // uniform addr: keep atomic load
    const int M = nc < CANDCAP ? (int)nc : CANDCAP;
    for (int i = tid; i < M; i += 256) sm.p2.sc[i] = cand[bb * CANDCAP + i];
    for (int i = tid; i < HBINS; i += 256) sm.p2.sh[i] = hist[bb * HBINS + i];
    __syncthreads();
    // top-16 rank under (key2, idx); distinct pairs -> unique ranks
    for (int j = tid; j < M; j += 256) {
      u64 me = sm.p2.sc[j];
      int r = 0;
      for (int t = 0; t < M; ++t) r += (sm.p2.sc[t] < me) ? 1 : 0;
      if (r < NK) sm.p2.Rt[r] = (uint32_t)(me & 0xffffffffu);
    }
    // parallel inclusive scan of sh -> S (8 bins/thread + block scan)
    uint32_t loc[8]; uint32_t run = 0;
    for (int j = 0; j < 8; ++j) { run += sm.p2.sh[tid * 8 + j]; loc[j] = run; }
    sm.p2.ts[tid] = run;
    __syncthreads();
    for (int off = 1; off < 256; off <<= 1) {
      uint32_t v = (tid >= off) ? sm.p2.ts[tid - off] : 0u;
      __syncthreads();
      sm.p2.ts[tid] += v;
      __syncthreads();
    }
    uint32_t excl = sm.p2.ts[tid] - run;
    for (int j = 0; j < 8; ++j) sm.p2.S[tid * 8 + j] = excl + loc[j];
    __syncthreads();
    if (tid < NK) {
      uint32_t R = sm.p2.Rt[tid];
      int lo = 0, hi = HBINS - 1;
      while (lo < hi) {                      // smallest i with S[i] > R
        int mid = (lo + hi) >> 1;
        if (sm.p2.S[mid] > R) hi = mid; else lo = mid + 1;
      }
      binsel[bb * NK + tid] = (uint32_t)lo;
      rem[bb * NK + tid] = R - (lo ? sm.p2.S[lo - 1] : 0u);
    }
  }
  gbar(bar, blk);

  // ---- P3: collect key1 elements landing in each target's bin ----
  {
    __shared__ uint32_t bs_s[NK];
    if (tid < NK) bs_s[tid] = binsel[b * NK + tid];
    __syncthreads();
    const int start = c * CHUNK;
    for (int i = start + tid; i < start + CHUNK; i += 256) {
      uint32_t k1 = sortkey(S1, (uint32_t)i);
      uint32_t pb = k1 >> 21;
      #pragma unroll
      for (int t = 0; t < NK; ++t) {
        if (pb == bs_s[t]) {
          uint32_t p = atomicAdd(&ncoll[b * NK + t], 1u);
          if (p < COLLCAP)
            coll[(b * NK + t) * COLLCAP + p] = ((u64)k1 << 32) | (uint32_t)i;
        }
      }
    }
  }
  gbar(bar, blk);

  // ---- P4 (blocks 0..63): stable rank-select, gather cent, zero sums[0] ----
  if (blk < NB) {
    const int bb = blk;
    for (int i = tid; i < NK * COLLCAP; i += 256)
      sm.p4.lc[i] = coll[bb * NK * COLLCAP + i];
    __syncthreads();
    if (tid < NK) {
      uint32_t ncl = ncoll[bb * NK + tid];
      const int m = ncl < COLLCAP ? (int)ncl : COLLCAP;
      const uint32_t r = rem[bb * NK + tid];
      const u64* cc = &sm.p4.lc[tid * COLLCAP];
      u64 lo = 0ULL, cur = ~0ULL;
      bool first = true;
      for (uint32_t pass = 0; pass <= r; ++pass) {
        cur = ~0ULL;
        for (int i = 0; i < m; ++i) {
          u64 v = cc[i];
          if ((first || v > lo) && v < cur) cur = v;
        }
        lo = cur; first = false;
      }
      sm.p4.jsel[tid] = (int)(cur & 0xffffffffu);
    }
    __syncthreads();
    if (tid < NK * NCH) {
      int k = tid / NCH, ch = tid % NCH;
      cent[bb * NK * NCH + tid] =
          x[((size_t)bb * NPIX + (size_t)sm.p4.jsel[k]) * NCH + ch];
    }
  }
  gbar(bar, blk);

  // ---- P5: 10 k-means iterations, 1 barrier each ----
  const float4* px4 = (const float4*)(x + (size_t)b * NPIX * NCH + (size_t)c * (CHUNK * NCH));
  float* accf = sm.p5.accf;

  for (int it = 0; it < NITER; ++it) {
    // (1) new centroids -> accf[0..47] scratch (redundant per block)
    if (tid < NK * NCH) {
      float v;
      if (it == 0) {
        v = cent[b * NK * NCH + tid];
      } else {
        const int k = tid / NCH, ch = tid - k * NCH;
        const double* sb = &sums[((it - 1) % 3) * (NB * NK * 4) + b * NK * 4];
        double s = sb[k * 4 + ch];
        double n = sb[k * 4 + 3];
        v = (float)(s / n);                  // 0/0 -> NaN, matching reference
      }
      accf[tid] = v;
    }
    __syncthreads();
    // (2) broadcast to registers; knan per-thread (batch-uniform result)
    float cr[NK * NCH];
    {
      const float4* cp = (const float4*)accf;
      #pragma unroll
      for (int i = 0; i < 12; ++i) {
        float4 t4 = cp[i];
        cr[4 * i + 0] = t4.x; cr[4 * i + 1] = t4.y;
        cr[4 * i + 2] = t4.z; cr[4 * i + 3] = t4.w;
      }
    }
    int kn = -1;
    #pragma unroll
    for (int k = NK - 1; k >= 0; --k) {      // descending so lowest k wins
      float a = cr[3 * k], bb2 = cr[3 * k + 1], cc2 = cr[3 * k + 2];
      if (a != a || bb2 != bb2 || cc2 != cc2) kn = k;
    }
    __syncthreads();
    // (3) zero accf + next-parity global buffer
    {
      float4 z4 = make_float4(0.f, 0.f, 0.f, 0.f);
      float4* zp = (float4*)accf;
      #pragma unroll
      for (int i = 0; i < 16; ++i) zp[tid + 256 * i] = z4;
      if (tid < NK * 4)
        sums[((it + 1) % 3) * (NB * NK * 4) + b * NK * 4 + tid] = 0.0;
    }
    __syncthreads();
    // (4) pixel loop: numpy-exact distances + argmin, private-column RMW
    float* a0 = &accf[tid];
    for (int j = tid; j < NQUADS; j += 256) {
      const float4 A = px4[3 * j], Bv = px4[3 * j + 1], Cv = px4[3 * j + 2];
      const float qx[4][3] = {{A.x, A.y, A.z}, {A.w, Bv.x, Bv.y},
                              {Bv.z, Bv.w, Cv.x}, {Cv.y, Cv.z, Cv.w}};
      #pragma unroll
      for (int q = 0; q < 4; ++q) {
        const float v0 = qx[q][0], v1 = qx[q][1], v2 = qx[q][2];
        int best = 0;
        float bd = 3.402823466e38f;
        #pragma unroll
        for (int k = 0; k < NK; ++k) {   // _rn chain, strict <, ascending k
          float d0 = __fsub_rn(v0, cr[3 * k + 0]);
          float d1 = __fsub_rn(v1, cr[3 * k + 1]);
          float d2 = __fsub_rn(v2, cr[3 * k + 2]);
          float d = __fadd_rn(__fadd_rn(__fmul_rn(d0, d0), __fmul_rn(d1, d1)),
                              __fmul_rn(d2, d2));
          bool cnd = d < bd;
          bd = cnd ? d : bd;
          best = cnd ? k : best;
        }
        if (kn >= 0) best = kn;          // np.argmin: first NaN wins
        const int r = best << 10;        // (best*4)*256 floats
        a0[r]       += v0;
        a0[r + 256] += v1;
        a0[r + 512] += v2;
        a0[r + 768] += 1.0f;
      }
    }
    __syncthreads();
    // (5) reduce: thread (r=tid&63, q=tid>>6) sums its 64-col row segment
    double part = 0.0;
    {
      const int r = tid & 63, q = tid >> 6;
      const float4* rp = (const float4*)&accf[r * 256 + q * 64];
      #pragma unroll
      for (int m = 0; m < 16; ++m) {
        float4 t4 = rp[m];
        part += (double)t4.x + (double)t4.y + (double)t4.z + (double)t4.w;
      }
    }
    __syncthreads();
    {
      double* red = (double*)accf;       // reuse rows 0-1 as f64 scratch
      red[tid] = part;
      __syncthreads();
      if (tid < 64) {
        double tot = red[tid] + red[64 + tid] + red[128 + tid] + red[192 + tid];
        atomicAdd(&sums[(it % 3) * (NB * NK * 4) + b * NK * 4 + tid], tot);
      }
    }
    gbar(bar, blk);
  }

  // final centroids -> out (chunk-0 blocks write)
  if (c == 0 && tid < NK * NCH) {
    const int k = tid / NCH, ch = tid - k * NCH;
    const double* sb = &sums[((NITER - 1) % 3) * (NB * NK * 4) + b * NK * 4];
    out[b * NK * NCH + tid] = (float)(sb[k * 4 + ch] / sb[k * 4 + 3]);
  }
}

// ---------------------------------------------------------------------------
// Fallback path (ws too small): R1-verified monolithic kinit + R2 loop.
// ---------------------------------------------------------------------------
__global__ __launch_bounds__(256) void kinit_mono(const float* __restrict__ x,
                                                  float* __restrict__ cent,
                                                  float* __restrict__ sums) {
  const int b = (int)blockIdx.x;
  const int tid = (int)threadIdx.x;
  __shared__ u64 cand[CANDCAP];
  __shared__ u64 coll[NK][COLLCAP];
  __shared__ uint32_t hist[HBINS];
  __shared__ uint32_t Rtgt[NK];
  __shared__ uint32_t binsel[NK];
  __shared__ uint32_t rem[NK];
  __shared__ int jsel[NK];
  __shared__ int ncand;
  __shared__ int ncoll[NK];
  KeyPair S1, S2;
  derive_keys(b, S1, S2);
  if (tid == 0) ncand = 0;
  if (tid < NK) ncoll[tid] = 0;
  for (int i = tid; i < HBINS; i += 256) hist[i] = 0u;
  __syncthreads();
  for (int i = tid; i < NPIX; i += 256) {
    uint32_t k2 = sortkey(S2, (uint32_t)i);
    if (k2 < T2VAL) {
      int p = atomicAdd(&ncand, 1);
      if (p < CANDCAP) cand[p] = ((u64)k2 << 32) | (uint32_t)i;
    }
    uint32_t k1 = sortkey(S1, (uint32_t)i);
    atomicAdd(&hist[k1 >> 21], 1u);
  }
  __syncthreads();
  const int M = ncand < CANDCAP ? ncand : CANDCAP;
  for (int j = tid; j < M; j += 256) {
    u64 me = cand[j];
    int rank = 0;
    for (int t = 0; t < M; ++t) rank += (cand[t] < me) ? 1 : 0;
    if (rank < NK) Rtgt[rank] = (uint32_t)(me & 0xffffffffu);
  }
  __syncthreads();
  if (tid < NK) {
    uint32_t R = Rtgt[tid], cum = 0u, bin = 0u;
    for (int i = 0; i < HBINS; ++i) {
      uint32_t h = hist[i];
      if (R < cum + h) { bin = (uint32_t)i; break; }
      cum += h;
    }
    binsel[tid] = bin;
    rem[tid] = R - cum;
  }
  __syncthreads();
  for (int i = tid; i < NPIX; i += 256) {
    uint32_t k1 = sortkey(S1, (uint32_t)i);
    uint32_t pb = k1 >> 21;
    #pragma unroll
    for (int t = 0; t < NK; ++t) {
      if (pb == binsel[t]) {
        int p = atomicAdd(&ncoll[t], 1);
        if (p < COLLCAP) coll[t][p] = ((u64)k1 << 32) | (uint32_t)i;
      }
    }
  }
  __syncthreads();
  if (tid < NK) {
    int m = ncoll[tid] < COLLCAP ? ncoll[tid] : COLLCAP;
    uint32_t r = rem[tid];
    u64 lo = 0ULL, cur = ~0ULL;
    bool first = true;
    for (uint32_t pass = 0; pass <= r; ++pass) {
      cur = ~0ULL;
      for (int t = 0; t < m; ++t) {
        u64 v = coll[tid][t];
        if ((first || v > lo) && v < cur) cur = v;
      }
      lo = cur; first = false;
    }
    jsel[tid] = (int)(cur & 0xffffffffu);
  }
  __syncthreads();
  if (tid < NK * NCH) {
    int k = tid / NCH, c = tid % NCH;
    cent[(b * NK + k) * NCH + c] = x[((size_t)b * NPIX + (size_t)jsel[k]) * NCH + c];
  }
  if (tid < NK * 4) sums[b * NK * 4 + tid] = 0.0f;
}

__global__ __launch_bounds__(256) void kassign(const float* __restrict__ x,
                                               const float* __restrict__ cent,
                                               float* __restrict__ sums) {
  const int b = (int)blockIdx.y;
  const int tid = (int)threadIdx.x;
  __shared__ float cs[NK * NCH];
  __shared__ float acc[4][NK * 4];
  __shared__ int knan_s;
  if (tid < NK * NCH) cs[tid] = cent[b * NK * NCH + tid];
  acc[tid >> 6][tid & 63] = 0.0f;
  __syncthreads();
  if (tid == 0) {
    int kn = -1;
    for (int k = 0; k < NK; ++k) {
      float a = cs[3 * k], bb = cs[3 * k + 1], cc = cs[3 * k + 2];
      if (a != a || bb != bb || cc != cc) { kn = k; break; }
    }
    knan_s = kn;
  }
  __syncthreads();
  float cr[NK * NCH];
  #pragma unroll
  for (int i = 0; i < NK * NCH; ++i) cr[i] = cs[i];
  const float* xb = x + (size_t)b * NPIX * NCH;
  const float4* p = (const float4*)(xb + (size_t)blockIdx.x * 3072);
  const float4 A = p[3 * tid], Bv = p[3 * tid + 1], Cv = p[3 * tid + 2];
  const float px[4][3] = {{A.x, A.y, A.z}, {A.w, Bv.x, Bv.y},
                          {Bv.z, Bv.w, Cv.x}, {Cv.y, Cv.z, Cv.w}};
  float* a0 = acc[tid >> 6];
  const int kn = knan_s;
  #pragma unroll
  for (int q = 0; q < 4; ++q) {
    const float v0 = px[q][0], v1 = px[q][1], v2 = px[q][2];
    int best = 0;
    float bd = 3.402823466e38f;
    #pragma unroll
    for (int k = 0; k < NK; ++k) {
      float d0 = __fsub_rn(v0, cr[3 * k + 0]);
      float d1 = __fsub_rn(v1, cr[3 * k + 1]);
      float d2 = __fsub_rn(v2, cr[3 * k + 2]);
      float d = __fadd_rn(__fadd_rn(__fmul_rn(d0, d0), __fmul_rn(d1, d1)),
                          __fmul_rn(d2, d2));
      bool cnd = d < bd;
      bd = cnd ? d : bd;
      best = cnd ? k : best;
    }
    if (kn >= 0) best = kn;
    atomicAdd(&a0[best * 4 + 0], v0);
    atomicAdd(&a0[best * 4 + 1], v1);
    atomicAdd(&a0[best * 4 + 2], v2);
    atomicAdd(&a0[best * 4 + 3], 1.0f);
  }
  __syncthreads();
  if (tid < NK * 4) {
    float v = acc[0][tid] + acc[1][tid] + acc[2][tid] + acc[3][tid];
    atomicAdd(&sums[b * NK * 4 + tid], v);
  }
}

__global__ __launch_bounds__(64) void kupdate(float* __restrict__ cent,
                                              float* __restrict__ sums,
                                              float* __restrict__ out) {
  const int b = (int)blockIdx.x;
  const int t = (int)threadIdx.x;
  float v = 0.0f;
  if (t < NK * NCH) {
    const int k = t / NCH, c = t % NCH;
    v = sums[b * NK * 4 + k * 4 + c] / sums[b * NK * 4 + k * 4 + 3];
  }
  __syncthreads();
  if (t < NK * NCH) {
    cent[b * NK * NCH + t] = v;
    out[b * NK * NCH + t] = v;
  }
  sums[b * NK * 4 + t] = 0.0f;
}

extern "C" void kernel_launch(void* const* d_in, const int* in_sizes, int n_in,
                              void* d_out, int out_size, void* d_ws, size_t ws_size,
                              hipStream_t stream) {
  (void)in_sizes; (void)n_in; (void)out_size;
  const float* x = (const float*)d_in[0];
  float* out = (float*)d_out;
  char* ws = (char*)d_ws;

  // ws layout (bytes)
  float*    cent   = (float*)(ws + 0);              // 12288
  double*   sums   = (double*)(ws + 12288);         // 98304 (3 parity bufs)
  uint32_t* ncand  = (uint32_t*)(ws + 110592);      // 256    } zero
  uint32_t* ncoll  = (uint32_t*)(ws + 110848);      // 4096   } zone
  uint32_t* bar    = (uint32_t*)(ws + 114944);      // 1024   } 110592..
  uint32_t* hist   = (uint32_t*)(ws + 115968);      // 524288 } ..640256
  uint32_t* binsel = (uint32_t*)(ws + 640256);      // 4096
  uint32_t* rem    = (uint32_t*)(ws + 644352);      // 4096
  u64*      cand   = (u64*)(ws + 648448);           // 524288
  u64*      coll   = (u64*)(ws + 1172736);          // 1048576
  const size_t REQ = 2221312;

  if (ws_size >= REQ) {
    hipMemsetAsync(ws + 110592, 0, 529664, stream);
    mega<<<NBLK, 256, 0, stream>>>(x, out, cent, sums, ncand, ncoll, bar,
                                   hist, binsel, rem, cand, coll);
  } else {
    float* centf = (float*)ws;                 // fallback: f32 sums layout
    float* sumsf = centf + NB * NK * NCH;
    kinit_mono<<<NB, 256, 0, stream>>>(x, centf, sumsf);
    for (int it = 0; it < NITER; ++it) {
      kassign<<<dim3(49, NB), 256, 0, stream>>>(x, centf, sumsf);
      kupdate<<<NB, 64, 0, stream>>>(centf, sumsf, out);
    }
  }
}

// Round 6
// 547.776 us; speedup vs baseline: 2.4818x; 1.2560x over previous
//
#include <hip/hip_runtime.h>
#include <stdint.h>

// ---------------------------------------------------------------------------
// ColorExtractor: per-image k-means (B=64, H*W=50176, C=3, K=16, 10 iters).
// Threefry2x32 bit-exact (verified R1, absmax 0.0).
// R6: remove the L2-invalidate from the 10 loop barriers. R5 kept one
// fence(ACQUIRE,"agent") per barrier = buffer_inv (L1+L2 discard) -> x-tiles
// evicted every iteration (FETCH 147MB = 3.8x input, VALUBusy 24%).
// Agent-scope RELEASE = buffer_wbl2 (writeback, KEEPS clean lines): loop
// barriers are now release-only arrival + relaxed spin + NO acquire; all
// cross-block loop data uses per-address agent atomic ld/st (bypass stale
// L1/L2). Init's 4 barriers keep full acquire (plain-access phases).
// Also: reduce-phase reads rotated (were 64-lanes-on-4-banks, 2.02e7
// conflict cycles).
// ---------------------------------------------------------------------------

#define NB    64
#define NPIX  50176
#define NK    16
#define NCH   3
#define NITER 10
#define HBINS 2048
#define CANDCAP 1024     // expect ~320 cands/batch (T2VAL), huge margin
#define COLLCAP 128      // expect ~24.5/bin
#define NBLK  512        // 8 chunks x 64 batches; 2 blocks/CU on 256 CUs
#define NGRP  8
#define GRPSZ (NBLK / NGRP)
#define CHUNK (NPIX / 8) // 6272 px per block-chunk
#define NQUADS (CHUNK / 4)

typedef unsigned long long u64;

struct KeyPair { uint32_t a, b; };

__device__ __forceinline__ uint32_t rotl32(uint32_t v, uint32_t r) {
  return (v << r) | (v >> (32u - r));
}
__device__ __forceinline__ void tf_round(uint32_t& x0, uint32_t& x1, uint32_t r) {
  x0 += x1; x1 = rotl32(x1, r); x1 ^= x0;
}

// Threefry-2x32, 20 rounds, exactly as jax/_src/prng.py lowering.
__device__ __forceinline__ KeyPair threefry(uint32_t k0, uint32_t k1,
                                            uint32_t x0, uint32_t x1) {
  const uint32_t ks2 = k0 ^ k1 ^ 0x1BD11BDAu;
  x0 += k0; x1 += k1;
  tf_round(x0, x1, 13u); tf_round(x0, x1, 15u); tf_round(x0, x1, 26u); tf_round(x0, x1, 6u);
  x0 += k1;  x1 += ks2 + 1u;
  tf_round(x0, x1, 17u); tf_round(x0, x1, 29u); tf_round(x0, x1, 16u); tf_round(x0, x1, 24u);
  x0 += ks2; x1 += k0 + 2u;
  tf_round(x0, x1, 13u); tf_round(x0, x1, 15u); tf_round(x0, x1, 26u); tf_round(x0, x1, 6u);
  x0 += k0;  x1 += k1 + 3u;
  tf_round(x0, x1, 17u); tf_round(x0, x1, 29u); tf_round(x0, x1, 16u); tf_round(x0, x1, 24u);
  x0 += k1;  x1 += ks2 + 4u;
  tf_round(x0, x1, 13u); tf_round(x0, x1, 15u); tf_round(x0, x1, 26u); tf_round(x0, x1, 6u);
  x0 += ks2; x1 += k0 + 5u;
  KeyPair r; r.a = x0; r.b = x1; return r;
}

__device__ __forceinline__ uint32_t sortkey(KeyPair S, uint32_t i) {
  KeyPair r = threefry(S.a, S.b, 0u, i);   // counter = 64-bit iota (hi=0,lo=i)
  return r.a ^ r.b;                        // 32-bit path XOR-folds the block
}

__device__ __forceinline__ void derive_keys(int b, KeyPair& S1, KeyPair& S2) {
  KeyPair root; root.a = 0u; root.b = 42u;
  KeyPair kb = threefry(root.a, root.b, 0u, (uint32_t)b);   // foldlike split
  KeyPair K1 = threefry(kb.a, kb.b, 0u, 0u);
  S1 = threefry(kb.a, kb.b, 0u, 1u);                        // round-1 subkey
  S2 = threefry(K1.a, K1.b, 0u, 1u);                        // round-2 subkey
}

#define T2VAL 27394240u  // ~2^32*320/NPIX

// ---- agent-scope per-address coherent accessors (bypass stale L1/L2) ------
__device__ __forceinline__ uint32_t ald_u32(const uint32_t* p) {
  return __hip_atomic_load(p, __ATOMIC_RELAXED, __HIP_MEMORY_SCOPE_AGENT);
}
__device__ __forceinline__ void ast_f64(double* p, double v) {
  __hip_atomic_store(p, v, __ATOMIC_RELAXED, __HIP_MEMORY_SCOPE_AGENT);
}
__device__ __forceinline__ double ald_f64(const double* p) {
  return __hip_atomic_load(p, __ATOMIC_RELAXED, __HIP_MEMORY_SCOPE_AGENT);
}

// bar layout (u32 idx): [g*16] group counters g=0..7 (64B apart),
// [128] root, [144] gen.

// Full barrier (init phases): release fence on arrival, acquire fence
// (buffer_inv) on exit. Plain loads/stores are safe across it. 4 uses only.
__device__ __forceinline__ void gbar_full(uint32_t* bar, int blk) {
  __syncthreads();
  if (threadIdx.x == 0) {
    uint32_t* grp  = bar + ((blk & (NGRP - 1)) << 4);
    uint32_t* root = bar + 128;
    uint32_t* gen  = bar + 144;
    uint32_t g = __hip_atomic_load(gen, __ATOMIC_RELAXED, __HIP_MEMORY_SCOPE_AGENT);
    __builtin_amdgcn_fence(__ATOMIC_RELEASE, "agent");  // wbl2: publish writes
    uint32_t a = __hip_atomic_fetch_add(grp, 1u, __ATOMIC_RELAXED,
                                        __HIP_MEMORY_SCOPE_AGENT);
    if (a == (uint32_t)GRPSZ - 1u) {
      __hip_atomic_store(grp, 0u, __ATOMIC_RELAXED, __HIP_MEMORY_SCOPE_AGENT);
      uint32_t r = __hip_atomic_fetch_add(root, 1u, __ATOMIC_RELAXED,
                                          __HIP_MEMORY_SCOPE_AGENT);
      if (r == (uint32_t)NGRP - 1u) {
        __hip_atomic_store(root, 0u, __ATOMIC_RELAXED, __HIP_MEMORY_SCOPE_AGENT);
        __hip_atomic_store(gen, g + 1u, __ATOMIC_RELEASE, __HIP_MEMORY_SCOPE_AGENT);
      } else {
        while (__hip_atomic_load(gen, __ATOMIC_RELAXED,
                                 __HIP_MEMORY_SCOPE_AGENT) == g)
          __builtin_amdgcn_s_sleep(1);
      }
    } else {
      while (__hip_atomic_load(gen, __ATOMIC_RELAXED,
                               __HIP_MEMORY_SCOPE_AGENT) == g)
        __builtin_amdgcn_s_sleep(1);
    }
    __builtin_amdgcn_fence(__ATOMIC_ACQUIRE, "agent");  // buffer_inv (once)
  }
  __syncthreads();
}

// Light barrier (k-means loop): release-only arrival (buffer_wbl2 keeps
// clean x lines in L2!), relaxed spin, NO acquire. All cross-block data
// accessed after this barrier MUST use agent atomic ld/st (ald/ast/atomicAdd).
__device__ __forceinline__ void gbar_light(uint32_t* bar, int blk) {
  __syncthreads();
  if (threadIdx.x == 0) {
    uint32_t* grp  = bar + ((blk & (NGRP - 1)) << 4);
    uint32_t* root = bar + 128;
    uint32_t* gen  = bar + 144;
    uint32_t g = __hip_atomic_load(gen, __ATOMIC_RELAXED, __HIP_MEMORY_SCOPE_AGENT);
    uint32_t a = __hip_atomic_fetch_add(grp, 1u, __ATOMIC_RELEASE,
                                        __HIP_MEMORY_SCOPE_AGENT);
    if (a == (uint32_t)GRPSZ - 1u) {
      uint32_t r = __hip_atomic_fetch_add(root, 1u, __ATOMIC_RELEASE,
                                          __HIP_MEMORY_SCOPE_AGENT);
      if (r == (uint32_t)NGRP - 1u) {
        __hip_atomic_store(root, 0u, __ATOMIC_RELAXED, __HIP_MEMORY_SCOPE_AGENT);
        __hip_atomic_store(grp, 0u, __ATOMIC_RELAXED, __HIP_MEMORY_SCOPE_AGENT);
        __hip_atomic_fetch_add(gen, 1u, __ATOMIC_RELAXED, __HIP_MEMORY_SCOPE_AGENT);
      } else {
        __hip_atomic_store(grp, 0u, __ATOMIC_RELAXED, __HIP_MEMORY_SCOPE_AGENT);
        while (__hip_atomic_load(gen, __ATOMIC_RELAXED,
                                 __HIP_MEMORY_SCOPE_AGENT) == g)
          __builtin_amdgcn_s_sleep(1);
      }
    } else {
      while (__hip_atomic_load(gen, __ATOMIC_RELAXED,
                               __HIP_MEMORY_SCOPE_AGENT) == g)
        __builtin_amdgcn_s_sleep(1);
    }
    // no acquire fence: x stays resident in L1/L2
  }
  __syncthreads();
}

union SMem {
  struct { uint32_t lh[HBINS]; } p1;
  struct { u64 sc[CANDCAP]; uint32_t sh[HBINS]; uint32_t S[HBINS];
           uint32_t ts[256]; uint32_t Rt[NK]; } p2;
  struct { uint32_t bs[NK]; } p3;
  struct { u64 lc[NK * COLLCAP]; int jsel[NK]; } p4;
  // 64 KB: row r = cluster*4+{c0,c1,c2,cnt}, column = tid (private -> no
  // atomics; bank = tid%32 always -> conflict-free).
  struct { float accf[64 * 256]; } p5;
};

__global__ __launch_bounds__(256, 2) void mega(
    const float* __restrict__ x, float* __restrict__ out,
    float* __restrict__ cent, double* __restrict__ sums,
    uint32_t* __restrict__ ncand, uint32_t* __restrict__ ncoll,
    uint32_t* __restrict__ bar, uint32_t* __restrict__ hist,
    uint32_t* __restrict__ binsel, uint32_t* __restrict__ rem,
    u64* __restrict__ cand, u64* __restrict__ coll) {
  __shared__ SMem sm;
  const int blk = (int)blockIdx.x;
  const int tid = (int)threadIdx.x;
  const int b = blk >> 3;        // batch
  const int c = blk & 7;         // chunk within batch

  KeyPair S1, S2;
  derive_keys(b, S1, S2);

  // ---- P1: key2 candidate filter + key1 prefix histogram ----
  for (int i = tid; i < HBINS; i += 256) sm.p1.lh[i] = 0u;
  __syncthreads();
  {
    const int start = c * CHUNK;
    for (int i = start + tid; i < start + CHUNK; i += 256) {
      uint32_t k2 = sortkey(S2, (uint32_t)i);
      if (k2 < T2VAL) {
        uint32_t p = atomicAdd(&ncand[b], 1u);
        if (p < CANDCAP) cand[b * CANDCAP + p] = ((u64)k2 << 32) | (uint32_t)i;
      }
      uint32_t k1 = sortkey(S1, (uint32_t)i);
      atomicAdd(&sm.p1.lh[k1 >> 21], 1u);
    }
    __syncthreads();
    for (int i = tid; i < HBINS; i += 256)
      if (sm.p1.lh[i]) atomicAdd(&hist[b * HBINS + i], sm.p1.lh[i]);
  }
  gbar_full(bar, blk);

  // ---- P2 (blocks 0..63): rank candidates, scan hist, binary search ----
  if (blk < NB) {
    const int bb = blk;
    uint32_t nc = ald_u32(&ncand[bb]);   // uniform addr: keep atomic load
    const int M = nc < CANDCAP ? (int)nc : CANDCAP;
    for (int i = tid; i < M; i += 256) sm.p2.sc[i] = cand[bb * CANDCAP + i];
    for (int i = tid; i < HBINS; i += 256) sm.p2.sh[i] = hist[bb * HBINS + i];
    __syncthreads();
    // top-16 rank under (key2, idx); distinct pairs -> unique ranks
    for (int j = tid; j < M; j += 256) {
      u64 me = sm.p2.sc[j];
      int r = 0;
      for (int t = 0; t < M; ++t) r += (sm.p2.sc[t] < me) ? 1 : 0;
      if (r < NK) sm.p2.Rt[r] = (uint32_t)(me & 0xffffffffu);
    }
    // parallel inclusive scan of sh -> S (8 bins/thread + block scan)
    uint32_t loc[8]; uint32_t run = 0;
    for (int j = 0; j < 8; ++j) { run += sm.p2.sh[tid * 8 + j]; loc[j] = run; }
    sm.p2.ts[tid] = run;
    __syncthreads();
    for (int off = 1; off < 256; off <<= 1) {
      uint32_t v = (tid >= off) ? sm.p2.ts[tid - off] : 0u;
      __syncthreads();
      sm.p2.ts[tid] += v;
      __syncthreads();
    }
    uint32_t excl = sm.p2.ts[tid] - run;
    for (int j = 0; j < 8; ++j) sm.p2.S[tid * 8 + j] = excl + loc[j];
    __syncthreads();
    if (tid < NK) {
      uint32_t R = sm.p2.Rt[tid];
      int lo = 0, hi = HBINS - 1;
      while (lo < hi) {                      // smallest i with S[i] > R
        int mid = (lo + hi) >> 1;
        if (sm.p2.S[mid] > R) hi = mid; else lo = mid + 1;
      }
      binsel[bb * NK + tid] = (uint32_t)lo;
      rem[bb * NK + tid] = R - (lo ? sm.p2.S[lo - 1] : 0u);
    }
  }
  gbar_full(bar, blk);

  // ---- P3: collect key1 elements landing in each target's bin ----
  {
    __shared__ uint32_t bs_s[NK];
    if (tid < NK) bs_s[tid] = binsel[b * NK + tid];
    __syncthreads();
    const int start = c * CHUNK;
    for (int i = start + tid; i < start + CHUNK; i += 256) {
      uint32_t k1 = sortkey(S1, (uint32_t)i);
      uint32_t pb = k1 >> 21;
      #pragma unroll
      for (int t = 0; t < NK; ++t) {
        if (pb == bs_s[t]) {
          uint32_t p = atomicAdd(&ncoll[b * NK + t], 1u);
          if (p < COLLCAP)
            coll[(b * NK + t) * COLLCAP + p] = ((u64)k1 << 32) | (uint32_t)i;
        }
      }
    }
  }
  gbar_full(bar, blk);

  // ---- P4 (blocks 0..63): stable rank-select, gather cent ----
  if (blk < NB) {
    const int bb = blk;
    for (int i = tid; i < NK * COLLCAP; i += 256)
      sm.p4.lc[i] = coll[bb * NK * COLLCAP + i];
    __syncthreads();
    if (tid < NK) {
      uint32_t ncl = ncoll[bb * NK + tid];
      const int m = ncl < COLLCAP ? (int)ncl : COLLCAP;
      const uint32_t r = rem[bb * NK + tid];
      const u64* cc = &sm.p4.lc[tid * COLLCAP];
      u64 lo = 0ULL, cur = ~0ULL;
      bool first = true;
      for (uint32_t pass = 0; pass <= r; ++pass) {
        cur = ~0ULL;
        for (int i = 0; i < m; ++i) {
          u64 v = cc[i];
          if ((first || v > lo) && v < cur) cur = v;
        }
        lo = cur; first = false;
      }
      sm.p4.jsel[tid] = (int)(cur & 0xffffffffu);
    }
    __syncthreads();
    if (tid < NK * NCH) {
      int k = tid / NCH, ch = tid % NCH;
      cent[bb * NK * NCH + tid] =
          x[((size_t)bb * NPIX + (size_t)sm.p4.jsel[k]) * NCH + ch];
    }
  }
  gbar_full(bar, blk);

  // ---- P5: 10 k-means iterations, 1 LIGHT barrier each ----
  // All cross-block traffic here via agent atomic ld/st + HW atomicAdd,
  // so no cache invalidation is needed -> x stays L2-resident.
  const float4* px4 = (const float4*)(x + (size_t)b * NPIX * NCH + (size_t)c * (CHUNK * NCH));
  float* accf = sm.p5.accf;

  for (int it = 0; it < NITER; ++it) {
    // (1) new centroids -> accf[0..47] scratch (redundant per block)
    if (tid < NK * NCH) {
      float v;
      if (it == 0) {
        v = cent[b * NK * NCH + tid];
      } else {
        const int k = tid / NCH, ch = tid - k * NCH;
        double* sb = &sums[((it - 1) % 3) * (NB * NK * 4) + b * NK * 4];
        double s = ald_f64(&sb[k * 4 + ch]);
        double n = ald_f64(&sb[k * 4 + 3]);
        v = (float)(s / n);                  // 0/0 -> NaN, matching reference
      }
      accf[tid] = v;
    }
    __syncthreads();
    // (2) broadcast to registers; knan per-thread (batch-uniform result)
    float cr[NK * NCH];
    {
      const float4* cp = (const float4*)accf;
      #pragma unroll
      for (int i = 0; i < 12; ++i) {
        float4 t4 = cp[i];
        cr[4 * i + 0] = t4.x; cr[4 * i + 1] = t4.y;
        cr[4 * i + 2] = t4.z; cr[4 * i + 3] = t4.w;
      }
    }
    int kn = -1;
    #pragma unroll
    for (int k = NK - 1; k >= 0; --k) {      // descending so lowest k wins
      float a = cr[3 * k], bb2 = cr[3 * k + 1], cc2 = cr[3 * k + 2];
      if (a != a || bb2 != bb2 || cc2 != cc2) kn = k;
    }
    __syncthreads();
    // (3) zero accf + next-parity global buffer (write-through atomic store)
    {
      float4 z4 = make_float4(0.f, 0.f, 0.f, 0.f);
      float4* zp = (float4*)accf;
      #pragma unroll
      for (int i = 0; i < 16; ++i) zp[tid + 256 * i] = z4;
      if (tid < NK * 4)
        ast_f64(&sums[((it + 1) % 3) * (NB * NK * 4) + b * NK * 4 + tid], 0.0);
    }
    __syncthreads();
    // (4) pixel loop: numpy-exact distances + argmin, private-column RMW
    float* a0 = &accf[tid];
    for (int j = tid; j < NQUADS; j += 256) {
      const float4 A = px4[3 * j], Bv = px4[3 * j + 1], Cv = px4[3 * j + 2];
      const float qx[4][3] = {{A.x, A.y, A.z}, {A.w, Bv.x, Bv.y},
                              {Bv.z, Bv.w, Cv.x}, {Cv.y, Cv.z, Cv.w}};
      #pragma unroll
      for (int q = 0; q < 4; ++q) {
        const float v0 = qx[q][0], v1 = qx[q][1], v2 = qx[q][2];
        int best = 0;
        float bd = 3.402823466e38f;
        #pragma unroll
        for (int k = 0; k < NK; ++k) {   // _rn chain, strict <, ascending k
          float d0 = __fsub_rn(v0, cr[3 * k + 0]);
          float d1 = __fsub_rn(v1, cr[3 * k + 1]);
          float d2 = __fsub_rn(v2, cr[3 * k + 2]);
          float d = __fadd_rn(__fadd_rn(__fmul_rn(d0, d0), __fmul_rn(d1, d1)),
                              __fmul_rn(d2, d2));
          bool cnd = d < bd;
          bd = cnd ? d : bd;
          best = cnd ? k : best;
        }
        if (kn >= 0) best = kn;          // np.argmin: first NaN wins
        const int r = best << 10;        // (best*4)*256 floats
        a0[r]       += v0;
        a0[r + 256] += v1;
        a0[r + 512] += v2;
        a0[r + 768] += 1.0f;
      }
    }
    __syncthreads();
    // (5) reduce: thread (r=tid&63, q=tid>>6) sums its 64-col row segment.
    // Rotated start (r&15) spreads lanes across banks (was: all 64 lanes of
    // a wave on the same 4 banks -> 2.02e7 conflict cycles).
    double part = 0.0;
    {
      const int r = tid & 63, q = tid >> 6;
      const float4* rp = (const float4*)&accf[r * 256 + q * 64];
      const int s0 = r & 15;
      #pragma unroll
      for (int m = 0; m < 16; ++m) {
        float4 t4 = rp[(m + s0) & 15];
        part += (double)t4.x + (double)t4.y + (double)t4.z + (double)t4.w;
      }
    }
    __syncthreads();
    {
      double* red = (double*)accf;       // reuse rows 0-3 as f64 scratch
      red[tid] = part;
      __syncthreads();
      if (tid < 64) {
        double tot = red[tid] + red[64 + tid] + red[128 + tid] + red[192 + tid];
        atomicAdd(&sums[(it % 3) * (NB * NK * 4) + b * NK * 4 + tid], tot);
      }
    }
    gbar_light(bar, blk);
  }

  // final centroids -> out (chunk-0 blocks write; coherent reads)
  if (c == 0 && tid < NK * NCH) {
    const int k = tid / NCH, ch = tid - k * NCH;
    double* sb = &sums[((NITER - 1) % 3) * (NB * NK * 4) + b * NK * 4];
    out[b * NK * NCH + tid] = (float)(ald_f64(&sb[k * 4 + ch]) /
                                      ald_f64(&sb[k * 4 + 3]));
  }
}

// ---------------------------------------------------------------------------
// Fallback path (ws too small): R1-verified monolithic kinit + R2 loop.
// ---------------------------------------------------------------------------
__global__ __launch_bounds__(256) void kinit_mono(const float* __restrict__ x,
                                                  float* __restrict__ cent,
                                                  float* __restrict__ sums) {
  const int b = (int)blockIdx.x;
  const int tid = (int)threadIdx.x;
  __shared__ u64 cand[CANDCAP];
  __shared__ u64 coll[NK][COLLCAP];
  __shared__ uint32_t hist[HBINS];
  __shared__ uint32_t Rtgt[NK];
  __shared__ uint32_t binsel[NK];
  __shared__ uint32_t rem[NK];
  __shared__ int jsel[NK];
  __shared__ int ncand;
  __shared__ int ncoll[NK];
  KeyPair S1, S2;
  derive_keys(b, S1, S2);
  if (tid == 0) ncand = 0;
  if (tid < NK) ncoll[tid] = 0;
  for (int i = tid; i < HBINS; i += 256) hist[i] = 0u;
  __syncthreads();
  for (int i = tid; i < NPIX; i += 256) {
    uint32_t k2 = sortkey(S2, (uint32_t)i);
    if (k2 < T2VAL) {
      int p = atomicAdd(&ncand, 1);
      if (p < CANDCAP) cand[p] = ((u64)k2 << 32) | (uint32_t)i;
    }
    uint32_t k1 = sortkey(S1, (uint32_t)i);
    atomicAdd(&hist[k1 >> 21], 1u);
  }
  __syncthreads();
  const int M = ncand < CANDCAP ? ncand : CANDCAP;
  for (int j = tid; j < M; j += 256) {
    u64 me = cand[j];
    int rank = 0;
    for (int t = 0; t < M; ++t) rank += (cand[t] < me) ? 1 : 0;
    if (rank < NK) Rtgt[rank] = (uint32_t)(me & 0xffffffffu);
  }
  __syncthreads();
  if (tid < NK) {
    uint32_t R = Rtgt[tid], cum = 0u, bin = 0u;
    for (int i = 0; i < HBINS; ++i) {
      uint32_t h = hist[i];
      if (R < cum + h) { bin = (uint32_t)i; break; }
      cum += h;
    }
    binsel[tid] = bin;
    rem[tid] = R - cum;
  }
  __syncthreads();
  for (int i = tid; i < NPIX; i += 256) {
    uint32_t k1 = sortkey(S1, (uint32_t)i);
    uint32_t pb = k1 >> 21;
    #pragma unroll
    for (int t = 0; t < NK; ++t) {
      if (pb == binsel[t]) {
        int p = atomicAdd(&ncoll[t], 1);
        if (p < COLLCAP) coll[t][p] = ((u64)k1 << 32) | (uint32_t)i;
      }
    }
  }
  __syncthreads();
  if (tid < NK) {
    int m = ncoll[tid] < COLLCAP ? ncoll[tid] : COLLCAP;
    uint32_t r = rem[tid];
    u64 lo = 0ULL, cur = ~0ULL;
    bool first = true;
    for (uint32_t pass = 0; pass <= r; ++pass) {
      cur = ~0ULL;
      for (int t = 0; t < m; ++t) {
        u64 v = coll[tid][t];
        if ((first || v > lo) && v < cur) cur = v;
      }
      lo = cur; first = false;
    }
    jsel[tid] = (int)(cur & 0xffffffffu);
  }
  __syncthreads();
  if (tid < NK * NCH) {
    int k = tid / NCH, c = tid % NCH;
    cent[(b * NK + k) * NCH + c] = x[((size_t)b * NPIX + (size_t)jsel[k]) * NCH + c];
  }
  if (tid < NK * 4) sums[b * NK * 4 + tid] = 0.0f;
}

__global__ __launch_bounds__(256) void kassign(const float* __restrict__ x,
                                               const float* __restrict__ cent,
                                               float* __restrict__ sums) {
  const int b = (int)blockIdx.y;
  const int tid = (int)threadIdx.x;
  __shared__ float cs[NK * NCH];
  __shared__ float acc[4][NK * 4];
  __shared__ int knan_s;
  if (tid < NK * NCH) cs[tid] = cent[b * NK * NCH + tid];
  acc[tid >> 6][tid & 63] = 0.0f;
  __syncthreads();
  if (tid == 0) {
    int kn = -1;
    for (int k = 0; k < NK; ++k) {
      float a = cs[3 * k], bb = cs[3 * k + 1], cc = cs[3 * k + 2];
      if (a != a || bb != bb || cc != cc) { kn = k; break; }
    }
    knan_s = kn;
  }
  __syncthreads();
  float cr[NK * NCH];
  #pragma unroll
  for (int i = 0; i < NK * NCH; ++i) cr[i] = cs[i];
  const float* xb = x + (size_t)b * NPIX * NCH;
  const float4* p = (const float4*)(xb + (size_t)blockIdx.x * 3072);
  const float4 A = p[3 * tid], Bv = p[3 * tid + 1], Cv = p[3 * tid + 2];
  const float px[4][3] = {{A.x, A.y, A.z}, {A.w, Bv.x, Bv.y},
                          {Bv.z, Bv.w, Cv.x}, {Cv.y, Cv.z, Cv.w}};
  float* a0 = acc[tid >> 6];
  const int kn = knan_s;
  #pragma unroll
  for (int q = 0; q < 4; ++q) {
    const float v0 = px[q][0], v1 = px[q][1], v2 = px[q][2];
    int best = 0;
    float bd = 3.402823466e38f;
    #pragma unroll
    for (int k = 0; k < NK; ++k) {
      float d0 = __fsub_rn(v0, cr[3 * k + 0]);
      float d1 = __fsub_rn(v1, cr[3 * k + 1]);
      float d2 = __fsub_rn(v2, cr[3 * k + 2]);
      float d = __fadd_rn(__fadd_rn(__fmul_rn(d0, d0), __fmul_rn(d1, d1)),
                          __fmul_rn(d2, d2));
      bool cnd = d < bd;
      bd = cnd ? d : bd;
      best = cnd ? k : best;
    }
    if (kn >= 0) best = kn;
    atomicAdd(&a0[best * 4 + 0], v0);
    atomicAdd(&a0[best * 4 + 1], v1);
    atomicAdd(&a0[best * 4 + 2], v2);
    atomicAdd(&a0[best * 4 + 3], 1.0f);
  }
  __syncthreads();
  if (tid < NK * 4) {
    float v = acc[0][tid] + acc[1][tid] + acc[2][tid] + acc[3][tid];
    atomicAdd(&sums[b * NK * 4 + tid], v);
  }
}

__global__ __launch_bounds__(64) void kupdate(float* __restrict__ cent,
                                              float* __restrict__ sums,
                                              float* __restrict__ out) {
  const int b = (int)blockIdx.x;
  const int t = (int)threadIdx.x;
  float v = 0.0f;
  if (t < NK * NCH) {
    const int k = t / NCH, c = t % NCH;
    v = sums[b * NK * 4 + k * 4 + c] / sums[b * NK * 4 + k * 4 + 3];
  }
  __syncthreads();
  if (t < NK * NCH) {
    cent[b * NK * NCH + t] = v;
    out[b * NK * NCH + t] = v;
  }
  sums[b * NK * 4 + t] = 0.0f;
}

extern "C" void kernel_launch(void* const* d_in, const int* in_sizes, int n_in,
                              void* d_out, int out_size, void* d_ws, size_t ws_size,
                              hipStream_t stream) {
  (void)in_sizes; (void)n_in; (void)out_size;
  const float* x = (const float*)d_in[0];
  float* out = (float*)d_out;
  char* ws = (char*)d_ws;

  // ws layout (bytes)
  float*    cent   = (float*)(ws + 0);              // 12288
  double*   sums   = (double*)(ws + 12288);         // 98304 (3 parity bufs)
  uint32_t* ncand  = (uint32_t*)(ws + 110592);      // 256    } zero
  uint32_t* ncoll  = (uint32_t*)(ws + 110848);      // 4096   } zone
  uint32_t* bar    = (uint32_t*)(ws + 114944);      // 1024   } 110592..
  uint32_t* hist   = (uint32_t*)(ws + 115968);      // 524288 } ..640256
  uint32_t* binsel = (uint32_t*)(ws + 640256);      // 4096
  uint32_t* rem    = (uint32_t*)(ws + 644352);      // 4096
  u64*      cand   = (u64*)(ws + 648448);           // 524288
  u64*      coll   = (u64*)(ws + 1172736);          // 1048576
  const size_t REQ = 2221312;

  if (ws_size >= REQ) {
    hipMemsetAsync(ws + 110592, 0, 529664, stream);
    mega<<<NBLK, 256, 0, stream>>>(x, out, cent, sums, ncand, ncoll, bar,
                                   hist, binsel, rem, cand, coll);
  } else {
    float* centf = (float*)ws;                 // fallback: f32 sums layout
    float* sumsf = centf + NB * NK * NCH;
    kinit_mono<<<NB, 256, 0, stream>>>(x, centf, sumsf);
    for (int it = 0; it < NITER; ++it) {
      kassign<<<dim3(49, NB), 256, 0, stream>>>(x, centf, sumsf);
      kupdate<<<NB, 64, 0, stream>>>(centf, sumsf, out);
    }
  }
}